// Round 9
// baseline (673.104 us; speedup 1.0000x reference)
//
#include <hip/hip_runtime.h>
#include <cstddef>
#include <cstdint>

#define NBATCH 8
#define NPTS   2048
#define KNN    20

typedef __attribute__((ext_vector_type(8))) short short8;
typedef __attribute__((ext_vector_type(4))) float f32x4;

__device__ __forceinline__ unsigned short f2bf(float f) {
  unsigned u = __float_as_uint(f);
  u += 0x7fff + ((u >> 16) & 1);   // round-to-nearest-even
  return (unsigned short)(u >> 16);
}
__device__ __forceinline__ float bf2f(unsigned short h) {
  return __uint_as_float(((unsigned)h) << 16);
}

// monotone float -> orderable uint (ascending uint == ascending float)
__device__ __forceinline__ unsigned f2ord(float f) {
  unsigned u = __float_as_uint(f);
  return (u & 0x80000000u) ? ~u : (u | 0x80000000u);
}

// ---------------------------------------------------------------------------
// slot -> global index mapping for wave_top20.
// MODE 0 (scalar loads): slot i on lane l -> i*64 + l
// MODE 1 (float4 loads): slot i=(c*4+j) on lane l -> c*256 + l*4 + j
// Selection keys (value, ~idx) are mapping-independent -> identical results.
// ---------------------------------------------------------------------------
template <int MODE>
__device__ __forceinline__ int slot_gidx(int i, int lane) {
  if constexpr (MODE == 0) return i * 64 + lane;
  else                     return (i >> 2) * 256 + lane * 4 + (i & 3);
}
template <int MODE>
__device__ __forceinline__ int lane_of_gidx(int idx) {
  if constexpr (MODE == 0) return idx & 63;
  else                     return (idx >> 2) & 63;
}
template <int MODE>
__device__ __forceinline__ int slot_of_gidx(int idx) {
  if constexpr (MODE == 0) return idx >> 6;
  else                     return ((idx >> 8) << 2) | (idx & 3);
}

// ---------------------------------------------------------------------------
// 64-lane bitonic sort, ascending across lanes. 21 compare-exchange stages.
// ---------------------------------------------------------------------------
template <typename T>
__device__ __forceinline__ T bitonic_sort_asc(T key, int lane) {
#pragma unroll
  for (int k = 2; k <= 64; k <<= 1) {
#pragma unroll
    for (int j = k >> 1; j > 0; j >>= 1) {
      T other = __shfl_xor(key, j);
      bool takemax = ((lane & k) == 0) != ((lane & j) == 0);
      key = takemax ? (key > other ? key : other)
                    : (key < other ? key : other);
    }
  }
  return key;
}

// ---------------------------------------------------------------------------
// exact serial fallback (ord-space port of the R15 top-2-cache extractor).
// Only taken when >64 values tie above the threshold -- effectively never.
// ---------------------------------------------------------------------------
template <int MODE>
__device__ void wave_top20_serial(const unsigned (&v)[32], int lane,
                                  int* __restrict__ row_out) {
  unsigned m1 = 0, m2 = 0;
  int i1 = 0, i2 = 0;
#pragma unroll
  for (int i = 0; i < 32; i++) {
    unsigned x = v[i];
    if (x > m1) { m2 = m1; i2 = i1; m1 = x; i1 = i; }
    else if (x > m2) { m2 = x; i2 = i; }
  }

  unsigned dm = 0;
  int cnt = 2;
  int keep = 0;
  for (int k = 0; k < KNN; k++) {
    unsigned rv = m1;
    int ri = slot_gidx<MODE>(i1, lane);
#pragma unroll
    for (int off = 32; off > 0; off >>= 1) {
      unsigned ov = __shfl_down(rv, off);
      int oi = __shfl_down(ri, off);
      if (ov > rv || (ov == rv && oi < ri)) { rv = ov; ri = oi; }
    }
    int wi = __shfl(ri, 0);
    if (lane == k) keep = wi;
    if (lane_of_gidx<MODE>(wi) == lane) {
      dm |= 1u << slot_of_gidx<MODE>(wi);
      if (cnt == 2) {
        m1 = m2; i1 = i2; cnt = 1;
      } else {
        m1 = 0; i1 = 0; m2 = 0; i2 = 0;
#pragma unroll
        for (int i = 0; i < 32; i++)
          if (!((dm >> i) & 1)) {
            unsigned x = v[i];
            if (x > m1) { m2 = m1; i2 = i1; m1 = x; i1 = i; }
            else if (x > m2) { m2 = x; i2 = i; }
          }
        cnt = 2;
      }
    }
  }
  if (lane < KNN) row_out[lane] = keep;
}

// ---------------------------------------------------------------------------
// wave-level exact top-20 over 2048 candidates (ord space). One wave per row.
// R17: threshold (20th-largest lane max) -> ballot-compact candidates into
// LDS -> one 64-lane bitonic sort of packed (value, ~index) keys emits the
// top-20 in order with the lowest-index tie-break.
// ---------------------------------------------------------------------------
template <int MODE>
__device__ __forceinline__ void wave_top20(const unsigned (&v)[32], int lane,
                                           unsigned long long* cand,
                                           int* __restrict__ row_out) {
  // 1. per-lane max
  unsigned mo = 0;
#pragma unroll
  for (int i = 0; i < 32; i++) mo = (v[i] > mo) ? v[i] : mo;

  // 2. sort the 64 lane maxima; T = 20th largest (ascending lane 44).
  unsigned ms = bitonic_sort_asc(mo, lane);
  unsigned T = __shfl(ms, 64 - KNN);

  // 3. ballot-compact all values >= T into LDS.
  cand[lane] = 0ull;
  int base = 0;
#pragma unroll
  for (int i = 0; i < 32; i++) {
    bool p = v[i] >= T;
    unsigned long long mk = __ballot(p);
    if (p) {
      int pos = base + __popcll(mk & ((1ull << lane) - 1ull));
      if (pos < 64)
        cand[pos] = ((unsigned long long)v[i] << 32) |
                    (unsigned)(~(unsigned)slot_gidx<MODE>(i, lane));
    }
    base += (int)__popcll(mk);
  }

  if (base <= 64) {
    // 4. one bitonic sort of packed keys; key = (ord << 32) | ~idx.
    unsigned long long key = cand[lane];
    key = bitonic_sort_asc(key, lane);
    if (lane >= 64 - KNN)
      row_out[63 - lane] = (int)(~(unsigned)key);
  } else {
    wave_top20_serial<MODE>(v, lane, row_out);
  }
}

// ---------------------------------------------------------------------------
// transpose (B,3,N) -> (B,N,3)
// ---------------------------------------------------------------------------
__global__ void k_transpose(const float* __restrict__ x, float* __restrict__ h0) {
  int i = blockIdx.x * 256 + threadIdx.x;
  if (i >= NBATCH * NPTS * 3) return;
  int c = i % 3;
  int n = (i / 3) % NPTS;
  int b = i / (3 * NPTS);
  h0[i] = x[((size_t)b * 3 + c) * NPTS + n];
}

// ---------------------------------------------------------------------------
// pairwise "distance" pd = 2*dot - sq_n - sq_m. blockIdx.z = batch in group.
// R11 64x64 tile / 4x4 microtile, upper-triangular grid; mirror via LDS
// bounce (bit-identical). R24/R25: microtile cols remapped c0+16j -> c0*4+j
// so dist stores are contiguous f32x4 NT stores (clang ext-vector -- HIP
// float4 is rejected by the NT builtin) and the bounce readback is b128
// (TS 67->68 for alignment; 2-way banks = free). Same values, same fma
// order -> bit-identical pd. NO chunk loops (R4/R5).
// ---------------------------------------------------------------------------
template <int C>
__global__ __launch_bounds__(256) void k_dist(const float* __restrict__ xg,
                                              float* __restrict__ dist) {
  constexpr int PAD = 4;
  constexpr int S = C + PAD;
  constexpr int TS = 68;
  __shared__ __attribute__((aligned(16))) float rows[64 * S];
  __shared__ __attribute__((aligned(16))) float cols[64 * S];
  __shared__ float sq[128];

  const float* xb = xg + (size_t)blockIdx.z * NPTS * C;
  float* db = dist + (size_t)blockIdx.z * NPTS * NPTS;

  constexpr int T = NPTS / 64;
  int bid = blockIdx.x;
  int rt = 0;
  while (bid >= T - rt) { bid -= T - rt; rt++; }
  const int ct = rt + bid;

  const int tid = threadIdx.x;

  for (int e = tid; e < 64 * C; e += 256) {
    int i = e / C, c = e - i * C;
    rows[i * S + c] = xb[(size_t)(rt * 64 + i) * C + c];
    cols[i * S + c] = xb[(size_t)(ct * 64 + i) * C + c];
  }
  __syncthreads();
  if (tid < 128) {
    const float* p = (tid < 64) ? (rows + tid * S) : (cols + (tid - 64) * S);
    float s = 0.f;
    for (int c = 0; c < C; c++) s += p[c] * p[c];
    sq[tid] = s;
  }
  __syncthreads();

  const int r0 = (tid >> 4) * 4;
  const int c0 = tid & 15;
  float acc[4][4] = {};

  for (int c = 0; c < C; c += 4) {
    float4 ra[4], cb[4];
#pragma unroll
    for (int i = 0; i < 4; i++) ra[i] = *(const float4*)&rows[(r0 + i) * S + c];
#pragma unroll
    for (int j = 0; j < 4; j++) cb[j] = *(const float4*)&cols[(c0 * 4 + j) * S + c];
#pragma unroll
    for (int i = 0; i < 4; i++)
#pragma unroll
      for (int j = 0; j < 4; j++)
        acc[i][j] += ra[i].x * cb[j].x + ra[i].y * cb[j].y +
                     ra[i].z * cb[j].z + ra[i].w * cb[j].w;
  }

  float pd[4][4];
#pragma unroll
  for (int i = 0; i < 4; i++) {
    float sr = sq[r0 + i];
#pragma unroll
    for (int j = 0; j < 4; j++)
      pd[i][j] = 2.f * acc[i][j] - sr - sq[64 + c0 * 4 + j];
  }

#pragma unroll
  for (int i = 0; i < 4; i++) {
    f32x4 o = {pd[i][0], pd[i][1], pd[i][2], pd[i][3]};
    __builtin_nontemporal_store(
        o, (f32x4*)&db[(size_t)(rt * 64 + r0 + i) * NPTS + ct * 64 + c0 * 4]);
  }

  if (rt != ct) {
    __syncthreads();
    float* tb = rows;   // 64*TS = 4352 == 64*S (C=64) -- exact fit
#pragma unroll
    for (int i = 0; i < 4; i++)
#pragma unroll
      for (int j = 0; j < 4; j++)
        tb[(c0 * 4 + j) * TS + r0 + i] = pd[i][j];
    __syncthreads();
#pragma unroll
    for (int i = 0; i < 4; i++) {
      f32x4 o = *(const f32x4*)&tb[(r0 + i) * TS + c0 * 4];
      __builtin_nontemporal_store(
          o, (f32x4*)&db[(size_t)(ct * 64 + r0 + i) * NPTS + rt * 64 + c0 * 4]);
    }
  }
}

// ---------------------------------------------------------------------------
// C=128 dist, single-pass, rows direct from global (R22: 16-lane broadcast,
// L1-resident; bit-identical pd). R24/R25: f32x4 col remap + NT stores.
// ---------------------------------------------------------------------------
__global__ __launch_bounds__(256) void k_dist128(const float* __restrict__ xg,
                                                 float* __restrict__ dist) {
  constexpr int C = 128;
  constexpr int S = C + 4;    // 132
  constexpr int TS = 68;
  __shared__ __attribute__((aligned(16))) float cols[64 * S];
  __shared__ float sq[128];

  const float* xb = xg + (size_t)blockIdx.z * NPTS * C;
  float* db = dist + (size_t)blockIdx.z * NPTS * NPTS;

  constexpr int T = NPTS / 64;
  int bid = blockIdx.x;
  int rt = 0;
  while (bid >= T - rt) { bid -= T - rt; rt++; }
  const int ct = rt + bid;

  const int tid = threadIdx.x;

  for (int e = tid; e < 64 * C; e += 256) {
    int i = e / C, c = e - i * C;
    cols[i * S + c] = xb[(size_t)(ct * 64 + i) * C + c];
  }
  // rows sq straight from global (same scalar ascending order as R11)
  float sr_own = 0.f;
  if (tid < 64) {
    const float* p = xb + (size_t)(rt * 64 + tid) * C;
    for (int c = 0; c < C; c++) sr_own += p[c] * p[c];
  }
  __syncthreads();
  if (tid < 128) {
    if (tid < 64) {
      sq[tid] = sr_own;
    } else {
      const float* p = cols + (tid - 64) * S;
      float s = 0.f;
      for (int c = 0; c < C; c++) s += p[c] * p[c];
      sq[tid] = s;
    }
  }
  __syncthreads();

  const int r0 = (tid >> 4) * 4;
  const int c0 = tid & 15;
  const float* xr0 = xb + (size_t)(rt * 64 + r0) * C;
  const float* xr1 = xr0 + C;
  const float* xr2 = xr1 + C;
  const float* xr3 = xr2 + C;
  float acc[4][4] = {};

  for (int c = 0; c < C; c += 4) {
    float4 ra[4], cb[4];
    ra[0] = *(const float4*)&xr0[c];
    ra[1] = *(const float4*)&xr1[c];
    ra[2] = *(const float4*)&xr2[c];
    ra[3] = *(const float4*)&xr3[c];
#pragma unroll
    for (int j = 0; j < 4; j++) cb[j] = *(const float4*)&cols[(c0 * 4 + j) * S + c];
#pragma unroll
    for (int i = 0; i < 4; i++)
#pragma unroll
      for (int j = 0; j < 4; j++)
        acc[i][j] += ra[i].x * cb[j].x + ra[i].y * cb[j].y +
                     ra[i].z * cb[j].z + ra[i].w * cb[j].w;
  }

  float pd[4][4];
#pragma unroll
  for (int i = 0; i < 4; i++) {
    float sr = sq[r0 + i];
#pragma unroll
    for (int j = 0; j < 4; j++)
      pd[i][j] = 2.f * acc[i][j] - sr - sq[64 + c0 * 4 + j];
  }

#pragma unroll
  for (int i = 0; i < 4; i++) {
    f32x4 o = {pd[i][0], pd[i][1], pd[i][2], pd[i][3]};
    __builtin_nontemporal_store(
        o, (f32x4*)&db[(size_t)(rt * 64 + r0 + i) * NPTS + ct * 64 + c0 * 4]);
  }

  if (rt != ct) {
    __syncthreads();   // all cols reads done before reuse as bounce buffer
    float* tb = cols;  // 64*TS = 4352 <= 64*S = 8448 floats
#pragma unroll
    for (int i = 0; i < 4; i++)
#pragma unroll
      for (int j = 0; j < 4; j++)
        tb[(c0 * 4 + j) * TS + r0 + i] = pd[i][j];
    __syncthreads();
#pragma unroll
    for (int i = 0; i < 4; i++) {
      f32x4 o = *(const f32x4*)&tb[(r0 + i) * TS + c0 * 4];
      __builtin_nontemporal_store(
          o, (f32x4*)&db[(size_t)(ct * 64 + r0 + i) * NPTS + rt * 64 + c0 * 4]);
    }
  }
}

// ---------------------------------------------------------------------------
// top-20 per row from materialized dist. One wave per row, 4 rows per block.
// R24: f32x4 NT reads (MODE 1 slot mapping -- selection keys unchanged).
// ---------------------------------------------------------------------------
__global__ __launch_bounds__(256) void k_topk(const float* __restrict__ dist,
                                              int* __restrict__ idx_out) {
  __shared__ unsigned long long cand[4][64];
  const int wid = threadIdx.x >> 6;
  const int lane = threadIdx.x & 63;
  const int n = blockIdx.x * 4 + wid;
  const int z = blockIdx.y;
  const float* drow = dist + ((size_t)z * NPTS + n) * NPTS;
  int* row_out = idx_out + ((size_t)z * NPTS + n) * KNN;

  unsigned v[32];
#pragma unroll
  for (int c = 0; c < 8; c++) {
    f32x4 f = __builtin_nontemporal_load(
        (const f32x4*)&drow[c * 256 + lane * 4]);
    v[c * 4 + 0] = f2ord(f[0]);
    v[c * 4 + 1] = f2ord(f[1]);
    v[c * 4 + 2] = f2ord(f[2]);
    v[c * 4 + 3] = f2ord(f[3]);
  }

  wave_top20<1>(v, lane, cand[wid], row_out);
}

// ---------------------------------------------------------------------------
// conv1 fused kNN (C=3): one wave per row, register recompute + wave_top20.
// ---------------------------------------------------------------------------
__global__ __launch_bounds__(256) void k_knn3(const float* __restrict__ x,
                                              int* __restrict__ idx_out) {
  __shared__ unsigned long long cand[4][64];
  const int wid = threadIdx.x >> 6;
  const int lane = threadIdx.x & 63;
  const int n = blockIdx.x * 4 + wid;
  const int b = blockIdx.y;
  const float* xb = x + (size_t)b * NPTS * 3;
  int* row_out = idx_out + ((size_t)b * NPTS + n) * KNN;

  const float qx = xb[n * 3 + 0], qy = xb[n * 3 + 1], qz = xb[n * 3 + 2];
  float qsq = 0.f;
  qsq += qx * qx; qsq += qy * qy; qsq += qz * qz;

  unsigned v[32];
#pragma unroll
  for (int i = 0; i < 32; i++) {
    int m = i * 64 + lane;
    float cx = xb[m * 3 + 0], cy = xb[m * 3 + 1], cz = xb[m * 3 + 2];
    float csq = 0.f;
    csq += cx * cx; csq += cy * cy; csq += cz * cz;
    float acc = 0.f;
    acc += qx * cx; acc += qy * cy; acc += qz * cz;
    v[i] = f2ord(2.f * acc - qsq - csq);
  }

  wave_top20<0>(v, lane, cand[wid], row_out);
}

// ---------------------------------------------------------------------------
// dual dense GEMM: blockIdx.z selects the w row-slice and output buffer.
//   z=0: out = ybuf,  wpart = w          (nb-ctr part)
//   z=1: out = t0buf, wpart = w + C*O    (ctr part)
// R18: gather commutes with the GEMM.
// ---------------------------------------------------------------------------
template <int C, int O>
__global__ __launch_bounds__(256) void k_t0(const float* __restrict__ x,
                                            const float* __restrict__ w,
                                            float* __restrict__ yb,
                                            float* __restrict__ t0b) {
  constexpr int TM = 128, TN = 64, TK = 16;
  __shared__ __attribute__((aligned(16))) float As[TK][TM + 4];
  __shared__ __attribute__((aligned(16))) float Bs[TK][TN + 4];
  const float* wpart = w + (size_t)blockIdx.z * C * O;
  float* outb = blockIdx.z ? t0b : yb;
  const int mt = blockIdx.x, nt = blockIdx.y;
  const int tid = threadIdx.x;
  const int tx = tid & 15, ty = tid >> 4;
  const size_t m0 = (size_t)mt * TM;
  const int n0 = nt * TN;
  float acc[8][4] = {};

  for (int kt = 0; kt < C; kt += TK) {
#pragma unroll
    for (int e = 0; e < 8; e++) {
      int idx = tid + e * 256;
      int m = idx >> 4, k = idx & 15;
      As[k][m] = x[(m0 + m) * C + kt + k];
    }
#pragma unroll
    for (int e = 0; e < 4; e++) {
      int idx = tid + e * 256;
      int k = idx >> 6, nn = idx & 63;
      Bs[k][nn] = wpart[(size_t)(kt + k) * O + n0 + nn];
    }
    __syncthreads();
#pragma unroll
    for (int kk = 0; kk < TK; kk++) {
      float4 a0 = *(const float4*)&As[kk][ty * 8];
      float4 a1 = *(const float4*)&As[kk][ty * 8 + 4];
      float4 b0 = *(const float4*)&Bs[kk][tx * 4];
      float av[8] = {a0.x, a0.y, a0.z, a0.w, a1.x, a1.y, a1.z, a1.w};
      float bb[4] = {b0.x, b0.y, b0.z, b0.w};
#pragma unroll
      for (int i = 0; i < 8; i++)
#pragma unroll
        for (int j = 0; j < 4; j++) acc[i][j] += av[i] * bb[j];
    }
    __syncthreads();
  }
#pragma unroll
  for (int i = 0; i < 8; i++)
#pragma unroll
    for (int j = 0; j < 4; j++)
      outb[(m0 + ty * 8 + i) * O + n0 + tx * 4 + j] = acc[i][j];
}

// ---------------------------------------------------------------------------
// conv1 tiny GEMM (C=3, O=64): one thread per (n,o), computes both the
// (nb-ctr) part y and the ctr part t0 in one pass.
// ---------------------------------------------------------------------------
__global__ void k_t3(const float* __restrict__ x, const float* __restrict__ w,
                     float* __restrict__ y, float* __restrict__ t0) {
  int i = blockIdx.x * 256 + threadIdx.x;
  if (i >= NBATCH * NPTS * 64) return;
  int o = i & 63;
  int n = i >> 6;
  float x0 = x[n * 3 + 0], x1v = x[n * 3 + 1], x2v = x[n * 3 + 2];
  y[i]  = x0 * w[0 * 64 + o] + x1v * w[1 * 64 + o] + x2v * w[2 * 64 + o];
  t0[i] = x0 * w[3 * 64 + o] + x1v * w[4 * 64 + o] + x2v * w[5 * 64 + o];
}

// ---------------------------------------------------------------------------
// edge conv epilogue: out[n,o] = max_k leaky((y[m_k,o] - y[n,o] + t0[n,o])
//                                            * g[o] + b[o]).
// Pure gather-max. grid MUST be NBATCH*NPTS/PPB (R19).
// ---------------------------------------------------------------------------
template <int O>
__global__ __launch_bounds__(256) void k_egather(
    const float* __restrict__ y, const float* __restrict__ t0,
    const int* __restrict__ knn, const float* __restrict__ g,
    const float* __restrict__ bta, float* __restrict__ out) {
  constexpr int TPP = O / 4;              // threads per point
  constexpr int PPB = 256 / TPP;          // points per block
  const int tid = threadIdx.x;
  const int pl = tid / TPP;
  const int oc = (tid % TPP) * 4;
  const int ptg = blockIdx.x * PPB + pl;  // global point index (b*NPTS+n)
  if (ptg >= NBATCH * NPTS) return;
  const int bb = ptg >> 11;               // NPTS = 2048
  const int* kp = knn + (size_t)ptg * KNN;
  const float* yb = y + (size_t)bb * NPTS * O;

  const float4 yc = *(const float4*)&y[(size_t)ptg * O + oc];
  const float4 tc = *(const float4*)&t0[(size_t)ptg * O + oc];
  const float4 gv = *(const float4*)&g[oc];
  const float4 bv = *(const float4*)&bta[oc];
  const float cx = tc.x - yc.x, cy = tc.y - yc.y;
  const float cz = tc.z - yc.z, cw = tc.w - yc.w;

  int midx[KNN];
#pragma unroll
  for (int k = 0; k < KNN; k++) midx[k] = kp[k];

  float4 vv[KNN];
#pragma unroll
  for (int k = 0; k < KNN; k++)
    vv[k] = *(const float4*)&yb[(size_t)midx[k] * O + oc];

  float m0 = -3.0e38f, m1 = -3.0e38f, m2 = -3.0e38f, m3 = -3.0e38f;
#pragma unroll
  for (int k = 0; k < KNN; k++) {
    float h0 = (vv[k].x + cx) * gv.x + bv.x;
    float h1 = (vv[k].y + cy) * gv.y + bv.y;
    float h2 = (vv[k].z + cz) * gv.z + bv.z;
    float h3 = (vv[k].w + cw) * gv.w + bv.w;
    h0 = (h0 >= 0.f) ? h0 : 0.2f * h0;
    h1 = (h1 >= 0.f) ? h1 : 0.2f * h1;
    h2 = (h2 >= 0.f) ? h2 : 0.2f * h2;
    h3 = (h3 >= 0.f) ? h3 : 0.2f * h3;
    m0 = fmaxf(m0, h0);
    m1 = fmaxf(m1, h1);
    m2 = fmaxf(m2, h2);
    m3 = fmaxf(m3, h3);
  }
  float4 res = {m0, m1, m2, m3};
  *(float4*)&out[(size_t)ptg * O + oc] = res;
}

// ---------------------------------------------------------------------------
// weight -> bf16 hi/lo split in 16x16x32 B-fragment order (mlp5 only).
// ---------------------------------------------------------------------------
template <int C, int O>
__global__ void k_wprep(const float* __restrict__ w,
                        unsigned short* __restrict__ whi,
                        unsigned short* __restrict__ wlo) {
  int e = blockIdx.x * 256 + threadIdx.x;
  if (e >= C * O) return;
  constexpr int NT = O / 16;
  int j = e & 7;
  int slot = e >> 3;
  int lane = slot & 63;
  int t2 = slot >> 6;
  int nt = t2 % NT, kb = t2 / NT;
  int k = kb * 32 + ((lane >> 4) & 3) * 8 + j;
  int n = nt * 16 + (lane & 15);
  float v = w[(size_t)k * O + n];
  unsigned short h = f2bf(v);
  unsigned short l = f2bf(v - bf2f(h));
  whi[e] = h;
  wlo[e] = l;
}

// ---------------------------------------------------------------------------
// feature matrix -> bf16 hi/lo split in 16x16x32 A-fragment order for mlp5.
// ---------------------------------------------------------------------------
__global__ void k_aprep(const float* __restrict__ x1, const float* __restrict__ x2,
                        const float* __restrict__ x3, const float* __restrict__ x4,
                        unsigned short* __restrict__ ah, unsigned short* __restrict__ al) {
  int e8 = blockIdx.x * 256 + threadIdx.x;
  if (e8 >= 16 * 1024 * 64) return;
  int lane = e8 & 63;
  int mtg = (e8 >> 6) & 1023;
  int kb = e8 >> 16;
  int m = mtg * 16 + (lane & 15);
  int k0 = kb * 32 + ((lane >> 4) & 3) * 8;
  const float* p;
  if (k0 < 64)       p = &x1[(size_t)m * 64 + k0];
  else if (k0 < 128) p = &x2[(size_t)m * 64 + (k0 - 64)];
  else if (k0 < 256) p = &x3[(size_t)m * 128 + (k0 - 128)];
  else               p = &x4[(size_t)m * 256 + (k0 - 256)];
  float4 f0 = *(const float4*)p;
  float4 f1 = *(const float4*)(p + 4);
  float fv[8] = {f0.x, f0.y, f0.z, f0.w, f1.x, f1.y, f1.z, f1.w};
  short8 h8, l8;
#pragma unroll
  for (int j = 0; j < 8; j++) {
    unsigned short h = f2bf(fv[j]);
    unsigned short l = f2bf(fv[j] - bf2f(h));
    h8[j] = (short)h;
    l8[j] = (short)l;
  }
  *(short8*)&ah[(size_t)e8 * 8] = h8;
  *(short8*)&al[(size_t)e8 * 8] = l8;
}

// ---------------------------------------------------------------------------
// point MLP 512->1024 as split-bf16 MFMA GEMM, no LDS, no barriers.
// ---------------------------------------------------------------------------
__global__ __launch_bounds__(256) void k_mlp5(const unsigned short* __restrict__ a5h,
                                              const unsigned short* __restrict__ a5l,
                                              const unsigned short* __restrict__ w5h,
                                              const unsigned short* __restrict__ w5l,
                                              const float* __restrict__ g5,
                                              const float* __restrict__ b5,
                                              float* __restrict__ pmax,
                                              float* __restrict__ psum) {
  const int mtb = blockIdx.x;
  const int ntb = blockIdx.y;
  const int tid = threadIdx.x;
  const int lane = tid & 63;
  const int nsl = tid >> 6;

  f32x4 acc[8][2];
#pragma unroll
  for (int mt = 0; mt < 8; mt++)
#pragma unroll
    for (int t = 0; t < 2; t++) acc[mt][t] = (f32x4){0.f, 0.f, 0.f, 0.f};

  for (int kb = 0; kb < 16; kb++) {
    short8 bh[2], bl[2];
#pragma unroll
    for (int t = 0; t < 2; t++) {
      int ntg = ntb * 8 + nsl * 2 + t;
      size_t widx = ((size_t)(kb * 64 + ntg) * 64 + lane) * 8;
      bh[t] = *(const short8*)&w5h[widx];
      bl[t] = *(const short8*)&w5l[widx];
    }
#pragma unroll
    for (int mt = 0; mt < 8; mt++) {
      size_t aidx = (((size_t)kb * 1024 + mtb * 8 + mt) * 64 + lane) * 8;
      short8 ah = *(const short8*)&a5h[aidx];
      short8 al = *(const short8*)&a5l[aidx];
#pragma unroll
      for (int t = 0; t < 2; t++) {
        acc[mt][t] = __builtin_amdgcn_mfma_f32_16x16x32_bf16(ah, bh[t], acc[mt][t], 0, 0, 0);
        acc[mt][t] = __builtin_amdgcn_mfma_f32_16x16x32_bf16(ah, bl[t], acc[mt][t], 0, 0, 0);
        acc[mt][t] = __builtin_amdgcn_mfma_f32_16x16x32_bf16(al, bh[t], acc[mt][t], 0, 0, 0);
      }
    }
  }

#pragma unroll
  for (int t = 0; t < 2; t++) {
    int o = ntb * 128 + (nsl * 2 + t) * 16 + (lane & 15);
    float gv = g5[o], bv = b5[o];
    float mx = -3.0e38f, sm = 0.f;
#pragma unroll
    for (int mt = 0; mt < 8; mt++)
#pragma unroll
      for (int r = 0; r < 4; r++) {
        float h = acc[mt][t][r] * gv + bv;
        h = (h >= 0.f) ? h : 0.2f * h;
        mx = fmaxf(mx, h);
        sm += h;
      }
    mx = fmaxf(mx, __shfl_xor(mx, 16));
    mx = fmaxf(mx, __shfl_xor(mx, 32));
    sm += __shfl_xor(sm, 16);
    sm += __shfl_xor(sm, 32);
    if (lane < 16) {
      pmax[(size_t)mtb * 1024 + o] = mx;
      psum[(size_t)mtb * 1024 + o] = sm;
    }
  }
}

// ---------------------------------------------------------------------------
// reduce tile partials -> pooled (B, 2048) = [max(1024), mean(1024)]
// ---------------------------------------------------------------------------
__global__ void k_pool(const float* __restrict__ pmax, const float* __restrict__ psum,
                       float* __restrict__ pooled) {
  int i = blockIdx.x * 256 + threadIdx.x;
  if (i >= NBATCH * 1024) return;
  int b = i / 1024, e = i - b * 1024;
  constexpr int NT = NPTS / 128;
  float mx = -3.0e38f, sm = 0.f;
  for (int t = 0; t < NT; t++) {
    mx = fmaxf(mx, pmax[((size_t)b * NT + t) * 1024 + e]);
    sm += psum[((size_t)b * NT + t) * 1024 + e];
  }
  pooled[(size_t)b * 2048 + e] = mx;
  pooled[(size_t)b * 2048 + 1024 + e] = sm * (1.0f / NPTS);
}

// ---------------------------------------------------------------------------
// head layer 1: h1g[b,o] = leaky((pooled[b,:] @ wl1)[o] * g6[o] + b6[o]).
// ---------------------------------------------------------------------------
__global__ __launch_bounds__(256) void k_head1(const float* __restrict__ pooled,
                                               const float* __restrict__ wl1,
                                               const float* __restrict__ g6,
                                               const float* __restrict__ b6,
                                               float* __restrict__ h1g) {
  const int os = blockIdx.x;
  const int b = blockIdx.y;
  const int tid = threadIdx.x;
  const int lane = tid & 63;
  const int ks = tid >> 6;
  const int o = os * 64 + lane;
  __shared__ float pl[2048];
  __shared__ float part[4][64];

  for (int i = tid; i < 2048; i += 256) pl[i] = pooled[(size_t)b * 2048 + i];
  __syncthreads();

  float a = 0.f;
  const int c0 = ks * 512;
  for (int c = 0; c < 512; c++)
    a += pl[c0 + c] * wl1[(size_t)(c0 + c) * 512 + o];
  part[ks][lane] = a;
  __syncthreads();

  if (ks == 0) {
    float s = part[0][lane];
    s += part[1][lane];
    s += part[2][lane];
    s += part[3][lane];
    s = s * g6[o] + b6[o];
    h1g[(size_t)b * 512 + o] = (s >= 0.f) ? s : 0.2f * s;
  }
}

// ---------------------------------------------------------------------------
// head layers 2+3: 512 ->(bias,affine,leaky) 256 -> 40 (+bias).
// ---------------------------------------------------------------------------
__global__ __launch_bounds__(256) void k_head23(const float* __restrict__ h1g,
                                                const float* __restrict__ wl2,
                                                const float* __restrict__ bl2,
                                                const float* __restrict__ g7,
                                                const float* __restrict__ b7,
                                                const float* __restrict__ wl3,
                                                const float* __restrict__ bl3,
                                                float* __restrict__ out) {
  const int b = blockIdx.x;
  const int tid = threadIdx.x;
  __shared__ float h1[512];
  __shared__ float h2[256];

  for (int i = tid; i < 512; i += 256) h1[i] = h1g[(size_t)b * 512 + i];
  __syncthreads();

  {
    float a = 0.f;
    for (int c = 0; c < 512; c++) a += h1[c] * wl2[(size_t)c * 256 + tid];
    a = (a + bl2[tid]) * g7[tid] + b7[tid];
    h2[tid] = (a >= 0.f) ? a : 0.2f * a;
  }
  __syncthreads();

  if (tid < 40) {
    float a = bl3[tid];
    for (int c = 0; c < 256; c++) a += h2[c] * wl3[(size_t)c * 40 + tid];
    out[(size_t)b * 40 + tid] = a;
  }
}

// ---------------------------------------------------------------------------
extern "C" void kernel_launch(void* const* d_in, const int* in_sizes, int n_in,
                              void* d_out, int out_size, void* d_ws, size_t ws_size,
                              hipStream_t stream) {
  (void)in_sizes; (void)n_in; (void)out_size;
  const float* x   = (const float*)d_in[0];
  const float* w1  = (const float*)d_in[1];
  const float* g1  = (const float*)d_in[2];
  const float* b1  = (const float*)d_in[3];
  const float* w2  = (const float*)d_in[4];
  const float* g2  = (const float*)d_in[5];
  const float* b2  = (const float*)d_in[6];
  const float* w3  = (const float*)d_in[7];
  const float* g3  = (const float*)d_in[8];
  const float* b3  = (const float*)d_in[9];
  const float* w4  = (const float*)d_in[10];
  const float* g4  = (const float*)d_in[11];
  const float* b4  = (const float*)d_in[12];
  const float* w5  = (const float*)d_in[13];
  const float* g5  = (const float*)d_in[14];
  const float* b5  = (const float*)d_in[15];
  const float* wl1 = (const float*)d_in[16];
  const float* g6  = (const float*)d_in[17];
  const float* b6  = (const float*)d_in[18];
  const float* wl2 = (const float*)d_in[19];
  const float* bl2 = (const float*)d_in[20];
  const float* g7  = (const float*)d_in[21];
  const float* b7  = (const float*)d_in[22];
  const float* wl3 = (const float*)d_in[23];
  const float* bl3 = (const float*)d_in[24];

  float* ws = (float*)d_ws;
  size_t off = 0;
  float* h0 = ws + off;   off += (size_t)NBATCH * NPTS * 3;
  float* x1 = ws + off;   off += (size_t)NBATCH * NPTS * 64;
  float* x2 = ws + off;   off += (size_t)NBATCH * NPTS * 64;
  float* x3 = ws + off;   off += (size_t)NBATCH * NPTS * 128;
  float* x4 = ws + off;   off += (size_t)NBATCH * NPTS * 256;
  int* knn = (int*)(ws + off); off += (size_t)NBATCH * NPTS * KNN;
  float* pmax = ws + off; off += (size_t)(NPTS / 128) * NBATCH * 1024;
  float* psum = ws + off; off += (size_t)(NPTS / 128) * NBATCH * 1024;
  float* pooled = ws + off; off += (size_t)NBATCH * 2048;
  float* h1g = ws + off;  off += (size_t)NBATCH * 512;
  float* t0buf = ws + off;  off += (size_t)NBATCH * NPTS * 256;  // max O
  unsigned short* w5h = (unsigned short*)(ws + off); off += 512 * 1024 / 2 * 2;
  unsigned short* w5l = w5h + 512 * 1024;
  unsigned short* a5h = (unsigned short*)(ws + off); off += (size_t)16384 * 512 / 2 * 2;
  unsigned short* a5l = a5h + (size_t)16384 * 512;
  float* dist = ws + off;  // adaptive: nb_grp * NPTS * NPTS floats, placed last

  // ybuf (max NBATCH*NPTS*256 floats) aliases the a5h/a5l region: it is dead
  // before k_aprep writes a5h (stream-serial), and the region is 2x larger.
  float* ybuf = (float*)a5h;

  size_t avail = ws_size / 4 - off;
  int nb_grp = 8;
  while (nb_grp > 1 && (size_t)nb_grp * NPTS * NPTS > avail) nb_grp >>= 1;

  constexpr int NTRI = (NPTS / 64) * (NPTS / 64 + 1) / 2;  // 528

  k_transpose<<<(NBATCH * NPTS * 3 + 255) / 256, 256, 0, stream>>>(x, h0);

  // mlp5 weight hi/lo fragment prep (depends only on inputs -- run up front)
  k_wprep<512, 1024><<<(512 * 1024 + 255) / 256, 256, 0, stream>>>(w5, w5h, w5l);

  // ---- edge conv 1 (C=3 -> O=64): fused register kNN + GEMM-gather
  k_knn3<<<dim3(NPTS / 4, NBATCH), 256, 0, stream>>>(h0, knn);
  k_t3<<<(NBATCH * NPTS * 64 + 255) / 256, 256, 0, stream>>>(h0, w1, ybuf, t0buf);
  k_egather<64><<<NBATCH * NPTS / 16, 256, 0, stream>>>(ybuf, t0buf, knn, g1, b1, x1);

  // ---- edge conv 2 (C=64 -> O=64)
  for (int b0 = 0; b0 < NBATCH; b0 += nb_grp) {
    k_dist<64><<<dim3(NTRI, 1, nb_grp), 256, 0, stream>>>(
        x1 + (size_t)b0 * NPTS * 64, dist);
    k_topk<<<dim3(NPTS / 4, nb_grp), 256, 0, stream>>>(dist,
                                                       knn + (size_t)b0 * NPTS * KNN);
  }
  k_t0<64, 64><<<dim3(NBATCH * NPTS / 128, 1, 2), 256, 0, stream>>>(x1, w2, ybuf,
                                                                    t0buf);
  k_egather<64><<<NBATCH * NPTS / 16, 256, 0, stream>>>(ybuf, t0buf, knn, g2, b2, x2);

  // ---- edge conv 3 (C=64 -> O=128)
  for (int b0 = 0; b0 < NBATCH; b0 += nb_grp) {
    k_dist<64><<<dim3(NTRI, 1, nb_grp), 256, 0, stream>>>(
        x2 + (size_t)b0 * NPTS * 64, dist);
    k_topk<<<dim3(NPTS / 4, nb_grp), 256, 0, stream>>>(dist,
                                                       knn + (size_t)b0 * NPTS * KNN);
  }
  k_t0<64, 128><<<dim3(NBATCH * NPTS / 128, 2, 2), 256, 0, stream>>>(x2, w3, ybuf,
                                                                     t0buf);
  k_egather<128><<<NBATCH * NPTS / 8, 256, 0, stream>>>(ybuf, t0buf, knn, g3, b3, x3);

  // ---- edge conv 4 (C=128 -> O=256)
  for (int b0 = 0; b0 < NBATCH; b0 += nb_grp) {
    k_dist128<<<dim3(NTRI, 1, nb_grp), 256, 0, stream>>>(
        x3 + (size_t)b0 * NPTS * 128, dist);
    k_topk<<<dim3(NPTS / 4, nb_grp), 256, 0, stream>>>(dist,
                                                       knn + (size_t)b0 * NPTS * KNN);
  }
  k_t0<128, 256><<<dim3(NBATCH * NPTS / 128, 4, 2), 256, 0, stream>>>(x3, w4, ybuf,
                                                                      t0buf);
  k_egather<256><<<NBATCH * NPTS / 4, 256, 0, stream>>>(ybuf, t0buf, knn, g4, b4, x4);

  // ---- point MLP (split-bf16 MFMA GEMM) + pooling + head
  k_aprep<<<(16 * 1024 * 64 + 255) / 256, 256, 0, stream>>>(x1, x2, x3, x4, a5h, a5l);
  k_mlp5<<<dim3(NBATCH * NPTS / 128, 8), 256, 0, stream>>>(a5h, a5l, w5h, w5l, g5, b5,
                                                           pmax, psum);
  k_pool<<<(NBATCH * 1024 + 255) / 256, 256, 0, stream>>>(pmax, psum, pooled);
  k_head1<<<dim3(8, NBATCH), 256, 0, stream>>>(pooled, wl1, g6, b6, h1g);
  k_head23<<<NBATCH, 256, 0, stream>>>(h1g, wl2, bl2, g7, b7, wl3, bl3,
                                       (float*)d_out);
}

// Round 10
// 659.722 us; speedup vs baseline: 1.0203x; 1.0203x over previous
//
#include <hip/hip_runtime.h>
#include <cstddef>
#include <cstdint>

#define NBATCH 8
#define NPTS   2048
#define KNN    20

typedef __attribute__((ext_vector_type(8))) short short8;
typedef __attribute__((ext_vector_type(4))) float f32x4;

__device__ __forceinline__ unsigned short f2bf(float f) {
  unsigned u = __float_as_uint(f);
  u += 0x7fff + ((u >> 16) & 1);   // round-to-nearest-even
  return (unsigned short)(u >> 16);
}
__device__ __forceinline__ float bf2f(unsigned short h) {
  return __uint_as_float(((unsigned)h) << 16);
}

// monotone float -> orderable uint (ascending uint == ascending float)
__device__ __forceinline__ unsigned f2ord(float f) {
  unsigned u = __float_as_uint(f);
  return (u & 0x80000000u) ? ~u : (u | 0x80000000u);
}

// ---------------------------------------------------------------------------
// slot -> global index mapping for wave_top20.
// MODE 0 (scalar loads): slot i on lane l -> i*64 + l
// MODE 1 (float4 loads): slot i=(c*4+j) on lane l -> c*256 + l*4 + j
// Selection keys (value, ~idx) are mapping-independent -> identical results.
// ---------------------------------------------------------------------------
template <int MODE>
__device__ __forceinline__ int slot_gidx(int i, int lane) {
  if constexpr (MODE == 0) return i * 64 + lane;
  else                     return (i >> 2) * 256 + lane * 4 + (i & 3);
}
template <int MODE>
__device__ __forceinline__ int lane_of_gidx(int idx) {
  if constexpr (MODE == 0) return idx & 63;
  else                     return (idx >> 2) & 63;
}
template <int MODE>
__device__ __forceinline__ int slot_of_gidx(int idx) {
  if constexpr (MODE == 0) return idx >> 6;
  else                     return ((idx >> 8) << 2) | (idx & 3);
}

// ---------------------------------------------------------------------------
// 64-lane bitonic sort, ascending across lanes. 21 compare-exchange stages.
// ---------------------------------------------------------------------------
template <typename T>
__device__ __forceinline__ T bitonic_sort_asc(T key, int lane) {
#pragma unroll
  for (int k = 2; k <= 64; k <<= 1) {
#pragma unroll
    for (int j = k >> 1; j > 0; j >>= 1) {
      T other = __shfl_xor(key, j);
      bool takemax = ((lane & k) == 0) != ((lane & j) == 0);
      key = takemax ? (key > other ? key : other)
                    : (key < other ? key : other);
    }
  }
  return key;
}

// ---------------------------------------------------------------------------
// exact serial fallback (ord-space port of the R15 top-2-cache extractor).
// Only taken when >64 values tie above the threshold -- effectively never.
// ---------------------------------------------------------------------------
template <int MODE>
__device__ void wave_top20_serial(const unsigned (&v)[32], int lane,
                                  int* __restrict__ row_out) {
  unsigned m1 = 0, m2 = 0;
  int i1 = 0, i2 = 0;
#pragma unroll
  for (int i = 0; i < 32; i++) {
    unsigned x = v[i];
    if (x > m1) { m2 = m1; i2 = i1; m1 = x; i1 = i; }
    else if (x > m2) { m2 = x; i2 = i; }
  }

  unsigned dm = 0;
  int cnt = 2;
  int keep = 0;
  for (int k = 0; k < KNN; k++) {
    unsigned rv = m1;
    int ri = slot_gidx<MODE>(i1, lane);
#pragma unroll
    for (int off = 32; off > 0; off >>= 1) {
      unsigned ov = __shfl_down(rv, off);
      int oi = __shfl_down(ri, off);
      if (ov > rv || (ov == rv && oi < ri)) { rv = ov; ri = oi; }
    }
    int wi = __shfl(ri, 0);
    if (lane == k) keep = wi;
    if (lane_of_gidx<MODE>(wi) == lane) {
      dm |= 1u << slot_of_gidx<MODE>(wi);
      if (cnt == 2) {
        m1 = m2; i1 = i2; cnt = 1;
      } else {
        m1 = 0; i1 = 0; m2 = 0; i2 = 0;
#pragma unroll
        for (int i = 0; i < 32; i++)
          if (!((dm >> i) & 1)) {
            unsigned x = v[i];
            if (x > m1) { m2 = m1; i2 = i1; m1 = x; i1 = i; }
            else if (x > m2) { m2 = x; i2 = i; }
          }
        cnt = 2;
      }
    }
  }
  if (lane < KNN) row_out[lane] = keep;
}

// ---------------------------------------------------------------------------
// wave-level exact top-20 over 2048 candidates (ord space). One wave per row.
// R17: threshold (20th-largest lane max) -> ballot-compact candidates into
// LDS -> one 64-lane bitonic sort of packed (value, ~index) keys emits the
// top-20 in order with the lowest-index tie-break.
// ---------------------------------------------------------------------------
template <int MODE>
__device__ __forceinline__ void wave_top20(const unsigned (&v)[32], int lane,
                                           unsigned long long* cand,
                                           int* __restrict__ row_out) {
  // 1. per-lane max
  unsigned mo = 0;
#pragma unroll
  for (int i = 0; i < 32; i++) mo = (v[i] > mo) ? v[i] : mo;

  // 2. sort the 64 lane maxima; T = 20th largest (ascending lane 44).
  unsigned ms = bitonic_sort_asc(mo, lane);
  unsigned T = __shfl(ms, 64 - KNN);

  // 3. ballot-compact all values >= T into LDS.
  cand[lane] = 0ull;
  int base = 0;
#pragma unroll
  for (int i = 0; i < 32; i++) {
    bool p = v[i] >= T;
    unsigned long long mk = __ballot(p);
    if (p) {
      int pos = base + __popcll(mk & ((1ull << lane) - 1ull));
      if (pos < 64)
        cand[pos] = ((unsigned long long)v[i] << 32) |
                    (unsigned)(~(unsigned)slot_gidx<MODE>(i, lane));
    }
    base += (int)__popcll(mk);
  }

  if (base <= 64) {
    // 4. one bitonic sort of packed keys; key = (ord << 32) | ~idx.
    unsigned long long key = cand[lane];
    key = bitonic_sort_asc(key, lane);
    if (lane >= 64 - KNN)
      row_out[63 - lane] = (int)(~(unsigned)key);
  } else {
    wave_top20_serial<MODE>(v, lane, row_out);
  }
}

// ---------------------------------------------------------------------------
// transpose (B,3,N) -> (B,N,3)
// ---------------------------------------------------------------------------
__global__ void k_transpose(const float* __restrict__ x, float* __restrict__ h0) {
  int i = blockIdx.x * 256 + threadIdx.x;
  if (i >= NBATCH * NPTS * 3) return;
  int c = i % 3;
  int n = (i / 3) % NPTS;
  int b = i / (3 * NPTS);
  h0[i] = x[((size_t)b * 3 + c) * NPTS + n];
}

// ---------------------------------------------------------------------------
// pairwise "distance" pd = 2*dot - sq_n - sq_m. blockIdx.z = batch in group.
// EXACT R23 form (best measured: 647 us total). R11 64x64 tile / 4x4
// microtile c0+16j (scalar NT stores are lane-contiguous -> already
// coalesced; R24/25 lesson: vectorizing them buys nothing and the col remap
// costs 8-way LDS conflicts). TS=67 (odd -> bounce-write bank spread).
// NO chunk loops (R4/R5). NT stores (R23: +4%).
// ---------------------------------------------------------------------------
template <int C>
__global__ __launch_bounds__(256) void k_dist(const float* __restrict__ xg,
                                              float* __restrict__ dist) {
  constexpr int PAD = 4;
  constexpr int S = C + PAD;
  constexpr int TS = 67;
  __shared__ __attribute__((aligned(16))) float rows[64 * S];
  __shared__ __attribute__((aligned(16))) float cols[64 * S];
  __shared__ float sq[128];

  const float* xb = xg + (size_t)blockIdx.z * NPTS * C;
  float* db = dist + (size_t)blockIdx.z * NPTS * NPTS;

  constexpr int T = NPTS / 64;
  int bid = blockIdx.x;
  int rt = 0;
  while (bid >= T - rt) { bid -= T - rt; rt++; }
  const int ct = rt + bid;

  const int tid = threadIdx.x;

  for (int e = tid; e < 64 * C; e += 256) {
    int i = e / C, c = e - i * C;
    rows[i * S + c] = xb[(size_t)(rt * 64 + i) * C + c];
    cols[i * S + c] = xb[(size_t)(ct * 64 + i) * C + c];
  }
  __syncthreads();
  if (tid < 128) {
    const float* p = (tid < 64) ? (rows + tid * S) : (cols + (tid - 64) * S);
    float s = 0.f;
    for (int c = 0; c < C; c++) s += p[c] * p[c];
    sq[tid] = s;
  }
  __syncthreads();

  const int r0 = (tid >> 4) * 4;
  const int c0 = tid & 15;
  float acc[4][4] = {};

  for (int c = 0; c < C; c += 4) {
    float4 ra[4], cb[4];
#pragma unroll
    for (int i = 0; i < 4; i++) ra[i] = *(const float4*)&rows[(r0 + i) * S + c];
#pragma unroll
    for (int j = 0; j < 4; j++) cb[j] = *(const float4*)&cols[(c0 + 16 * j) * S + c];
#pragma unroll
    for (int i = 0; i < 4; i++)
#pragma unroll
      for (int j = 0; j < 4; j++)
        acc[i][j] += ra[i].x * cb[j].x + ra[i].y * cb[j].y +
                     ra[i].z * cb[j].z + ra[i].w * cb[j].w;
  }

  float pd[4][4];
#pragma unroll
  for (int i = 0; i < 4; i++) {
    float sr = sq[r0 + i];
#pragma unroll
    for (int j = 0; j < 4; j++)
      pd[i][j] = 2.f * acc[i][j] - sr - sq[64 + c0 + 16 * j];
  }

#pragma unroll
  for (int i = 0; i < 4; i++)
#pragma unroll
    for (int j = 0; j < 4; j++)
      __builtin_nontemporal_store(
          pd[i][j], &db[(size_t)(rt * 64 + r0 + i) * NPTS + ct * 64 + c0 + 16 * j]);

  if (rt != ct) {
    __syncthreads();
    float* tb = rows;
#pragma unroll
    for (int i = 0; i < 4; i++)
#pragma unroll
      for (int j = 0; j < 4; j++)
        tb[(c0 + 16 * j) * TS + r0 + i] = pd[i][j];
    __syncthreads();
#pragma unroll
    for (int i = 0; i < 4; i++)
#pragma unroll
      for (int j = 0; j < 4; j++)
        __builtin_nontemporal_store(
            tb[(r0 + i) * TS + c0 + 16 * j],
            &db[(size_t)(ct * 64 + r0 + i) * NPTS + rt * 64 + c0 + 16 * j]);
  }
}

// ---------------------------------------------------------------------------
// C=128 dist, single-pass, rows direct from global (R22: 16-lane broadcast,
// L1-resident; bit-identical pd). EXACT R23 form. NT scalar stores.
// ---------------------------------------------------------------------------
__global__ __launch_bounds__(256) void k_dist128(const float* __restrict__ xg,
                                                 float* __restrict__ dist) {
  constexpr int C = 128;
  constexpr int S = C + 4;    // 132
  constexpr int TS = 67;
  __shared__ __attribute__((aligned(16))) float cols[64 * S];
  __shared__ float sq[128];

  const float* xb = xg + (size_t)blockIdx.z * NPTS * C;
  float* db = dist + (size_t)blockIdx.z * NPTS * NPTS;

  constexpr int T = NPTS / 64;
  int bid = blockIdx.x;
  int rt = 0;
  while (bid >= T - rt) { bid -= T - rt; rt++; }
  const int ct = rt + bid;

  const int tid = threadIdx.x;

  for (int e = tid; e < 64 * C; e += 256) {
    int i = e / C, c = e - i * C;
    cols[i * S + c] = xb[(size_t)(ct * 64 + i) * C + c];
  }
  // rows sq straight from global (same scalar ascending order as R11)
  float sr_own = 0.f;
  if (tid < 64) {
    const float* p = xb + (size_t)(rt * 64 + tid) * C;
    for (int c = 0; c < C; c++) sr_own += p[c] * p[c];
  }
  __syncthreads();
  if (tid < 128) {
    if (tid < 64) {
      sq[tid] = sr_own;
    } else {
      const float* p = cols + (tid - 64) * S;
      float s = 0.f;
      for (int c = 0; c < C; c++) s += p[c] * p[c];
      sq[tid] = s;
    }
  }
  __syncthreads();

  const int r0 = (tid >> 4) * 4;
  const int c0 = tid & 15;
  const float* xr0 = xb + (size_t)(rt * 64 + r0) * C;
  const float* xr1 = xr0 + C;
  const float* xr2 = xr1 + C;
  const float* xr3 = xr2 + C;
  float acc[4][4] = {};

  for (int c = 0; c < C; c += 4) {
    float4 ra[4], cb[4];
    ra[0] = *(const float4*)&xr0[c];
    ra[1] = *(const float4*)&xr1[c];
    ra[2] = *(const float4*)&xr2[c];
    ra[3] = *(const float4*)&xr3[c];
#pragma unroll
    for (int j = 0; j < 4; j++) cb[j] = *(const float4*)&cols[(c0 + 16 * j) * S + c];
#pragma unroll
    for (int i = 0; i < 4; i++)
#pragma unroll
      for (int j = 0; j < 4; j++)
        acc[i][j] += ra[i].x * cb[j].x + ra[i].y * cb[j].y +
                     ra[i].z * cb[j].z + ra[i].w * cb[j].w;
  }

  float pd[4][4];
#pragma unroll
  for (int i = 0; i < 4; i++) {
    float sr = sq[r0 + i];
#pragma unroll
    for (int j = 0; j < 4; j++)
      pd[i][j] = 2.f * acc[i][j] - sr - sq[64 + c0 + 16 * j];
  }

#pragma unroll
  for (int i = 0; i < 4; i++)
#pragma unroll
    for (int j = 0; j < 4; j++)
      __builtin_nontemporal_store(
          pd[i][j], &db[(size_t)(rt * 64 + r0 + i) * NPTS + ct * 64 + c0 + 16 * j]);

  if (rt != ct) {
    __syncthreads();   // all cols reads done before reuse as bounce buffer
    float* tb = cols;  // 64*TS = 4288 <= 64*S = 8448 floats
#pragma unroll
    for (int i = 0; i < 4; i++)
#pragma unroll
      for (int j = 0; j < 4; j++)
        tb[(c0 + 16 * j) * TS + r0 + i] = pd[i][j];
    __syncthreads();
#pragma unroll
    for (int i = 0; i < 4; i++)
#pragma unroll
      for (int j = 0; j < 4; j++)
        __builtin_nontemporal_store(
            tb[(r0 + i) * TS + c0 + 16 * j],
            &db[(size_t)(ct * 64 + r0 + i) * NPTS + rt * 64 + c0 + 16 * j]);
  }
}

// ---------------------------------------------------------------------------
// top-20 per row from materialized dist. One wave per row, 4 rows per block.
// R25 piece kept: f32x4 NT reads (4x fewer load instructions, 1KB/instr
// coalescing; works with any row-major dist producer). MODE 1 slot mapping
// keeps selection keys identical.
// ---------------------------------------------------------------------------
__global__ __launch_bounds__(256) void k_topk(const float* __restrict__ dist,
                                              int* __restrict__ idx_out) {
  __shared__ unsigned long long cand[4][64];
  const int wid = threadIdx.x >> 6;
  const int lane = threadIdx.x & 63;
  const int n = blockIdx.x * 4 + wid;
  const int z = blockIdx.y;
  const float* drow = dist + ((size_t)z * NPTS + n) * NPTS;
  int* row_out = idx_out + ((size_t)z * NPTS + n) * KNN;

  unsigned v[32];
#pragma unroll
  for (int c = 0; c < 8; c++) {
    f32x4 f = __builtin_nontemporal_load(
        (const f32x4*)&drow[c * 256 + lane * 4]);
    v[c * 4 + 0] = f2ord(f[0]);
    v[c * 4 + 1] = f2ord(f[1]);
    v[c * 4 + 2] = f2ord(f[2]);
    v[c * 4 + 3] = f2ord(f[3]);
  }

  wave_top20<1>(v, lane, cand[wid], row_out);
}

// ---------------------------------------------------------------------------
// conv1 fused kNN (C=3): one wave per row, register recompute + wave_top20.
// ---------------------------------------------------------------------------
__global__ __launch_bounds__(256) void k_knn3(const float* __restrict__ x,
                                              int* __restrict__ idx_out) {
  __shared__ unsigned long long cand[4][64];
  const int wid = threadIdx.x >> 6;
  const int lane = threadIdx.x & 63;
  const int n = blockIdx.x * 4 + wid;
  const int b = blockIdx.y;
  const float* xb = x + (size_t)b * NPTS * 3;
  int* row_out = idx_out + ((size_t)b * NPTS + n) * KNN;

  const float qx = xb[n * 3 + 0], qy = xb[n * 3 + 1], qz = xb[n * 3 + 2];
  float qsq = 0.f;
  qsq += qx * qx; qsq += qy * qy; qsq += qz * qz;

  unsigned v[32];
#pragma unroll
  for (int i = 0; i < 32; i++) {
    int m = i * 64 + lane;
    float cx = xb[m * 3 + 0], cy = xb[m * 3 + 1], cz = xb[m * 3 + 2];
    float csq = 0.f;
    csq += cx * cx; csq += cy * cy; csq += cz * cz;
    float acc = 0.f;
    acc += qx * cx; acc += qy * cy; acc += qz * cz;
    v[i] = f2ord(2.f * acc - qsq - csq);
  }

  wave_top20<0>(v, lane, cand[wid], row_out);
}

// ---------------------------------------------------------------------------
// dual dense GEMM: blockIdx.z selects the w row-slice and output buffer.
//   z=0: out = ybuf,  wpart = w          (nb-ctr part)
//   z=1: out = t0buf, wpart = w + C*O    (ctr part)
// R18: gather commutes with the GEMM.
// ---------------------------------------------------------------------------
template <int C, int O>
__global__ __launch_bounds__(256) void k_t0(const float* __restrict__ x,
                                            const float* __restrict__ w,
                                            float* __restrict__ yb,
                                            float* __restrict__ t0b) {
  constexpr int TM = 128, TN = 64, TK = 16;
  __shared__ __attribute__((aligned(16))) float As[TK][TM + 4];
  __shared__ __attribute__((aligned(16))) float Bs[TK][TN + 4];
  const float* wpart = w + (size_t)blockIdx.z * C * O;
  float* outb = blockIdx.z ? t0b : yb;
  const int mt = blockIdx.x, nt = blockIdx.y;
  const int tid = threadIdx.x;
  const int tx = tid & 15, ty = tid >> 4;
  const size_t m0 = (size_t)mt * TM;
  const int n0 = nt * TN;
  float acc[8][4] = {};

  for (int kt = 0; kt < C; kt += TK) {
#pragma unroll
    for (int e = 0; e < 8; e++) {
      int idx = tid + e * 256;
      int m = idx >> 4, k = idx & 15;
      As[k][m] = x[(m0 + m) * C + kt + k];
    }
#pragma unroll
    for (int e = 0; e < 4; e++) {
      int idx = tid + e * 256;
      int k = idx >> 6, nn = idx & 63;
      Bs[k][nn] = wpart[(size_t)(kt + k) * O + n0 + nn];
    }
    __syncthreads();
#pragma unroll
    for (int kk = 0; kk < TK; kk++) {
      float4 a0 = *(const float4*)&As[kk][ty * 8];
      float4 a1 = *(const float4*)&As[kk][ty * 8 + 4];
      float4 b0 = *(const float4*)&Bs[kk][tx * 4];
      float av[8] = {a0.x, a0.y, a0.z, a0.w, a1.x, a1.y, a1.z, a1.w};
      float bb[4] = {b0.x, b0.y, b0.z, b0.w};
#pragma unroll
      for (int i = 0; i < 8; i++)
#pragma unroll
        for (int j = 0; j < 4; j++) acc[i][j] += av[i] * bb[j];
    }
    __syncthreads();
  }
#pragma unroll
  for (int i = 0; i < 8; i++)
#pragma unroll
    for (int j = 0; j < 4; j++)
      outb[(m0 + ty * 8 + i) * O + n0 + tx * 4 + j] = acc[i][j];
}

// ---------------------------------------------------------------------------
// conv1 tiny GEMM (C=3, O=64): one thread per (n,o), computes both the
// (nb-ctr) part y and the ctr part t0 in one pass.
// ---------------------------------------------------------------------------
__global__ void k_t3(const float* __restrict__ x, const float* __restrict__ w,
                     float* __restrict__ y, float* __restrict__ t0) {
  int i = blockIdx.x * 256 + threadIdx.x;
  if (i >= NBATCH * NPTS * 64) return;
  int o = i & 63;
  int n = i >> 6;
  float x0 = x[n * 3 + 0], x1v = x[n * 3 + 1], x2v = x[n * 3 + 2];
  y[i]  = x0 * w[0 * 64 + o] + x1v * w[1 * 64 + o] + x2v * w[2 * 64 + o];
  t0[i] = x0 * w[3 * 64 + o] + x1v * w[4 * 64 + o] + x2v * w[5 * 64 + o];
}

// ---------------------------------------------------------------------------
// edge conv epilogue: out[n,o] = max_k leaky((y[m_k,o] - y[n,o] + t0[n,o])
//                                            * g[o] + b[o]).
// Pure gather-max. grid MUST be NBATCH*NPTS/PPB (R19).
// ---------------------------------------------------------------------------
template <int O>
__global__ __launch_bounds__(256) void k_egather(
    const float* __restrict__ y, const float* __restrict__ t0,
    const int* __restrict__ knn, const float* __restrict__ g,
    const float* __restrict__ bta, float* __restrict__ out) {
  constexpr int TPP = O / 4;              // threads per point
  constexpr int PPB = 256 / TPP;          // points per block
  const int tid = threadIdx.x;
  const int pl = tid / TPP;
  const int oc = (tid % TPP) * 4;
  const int ptg = blockIdx.x * PPB + pl;  // global point index (b*NPTS+n)
  if (ptg >= NBATCH * NPTS) return;
  const int bb = ptg >> 11;               // NPTS = 2048
  const int* kp = knn + (size_t)ptg * KNN;
  const float* yb = y + (size_t)bb * NPTS * O;

  const float4 yc = *(const float4*)&y[(size_t)ptg * O + oc];
  const float4 tc = *(const float4*)&t0[(size_t)ptg * O + oc];
  const float4 gv = *(const float4*)&g[oc];
  const float4 bv = *(const float4*)&bta[oc];
  const float cx = tc.x - yc.x, cy = tc.y - yc.y;
  const float cz = tc.z - yc.z, cw = tc.w - yc.w;

  int midx[KNN];
#pragma unroll
  for (int k = 0; k < KNN; k++) midx[k] = kp[k];

  float4 vv[KNN];
#pragma unroll
  for (int k = 0; k < KNN; k++)
    vv[k] = *(const float4*)&yb[(size_t)midx[k] * O + oc];

  float m0 = -3.0e38f, m1 = -3.0e38f, m2 = -3.0e38f, m3 = -3.0e38f;
#pragma unroll
  for (int k = 0; k < KNN; k++) {
    float h0 = (vv[k].x + cx) * gv.x + bv.x;
    float h1 = (vv[k].y + cy) * gv.y + bv.y;
    float h2 = (vv[k].z + cz) * gv.z + bv.z;
    float h3 = (vv[k].w + cw) * gv.w + bv.w;
    h0 = (h0 >= 0.f) ? h0 : 0.2f * h0;
    h1 = (h1 >= 0.f) ? h1 : 0.2f * h1;
    h2 = (h2 >= 0.f) ? h2 : 0.2f * h2;
    h3 = (h3 >= 0.f) ? h3 : 0.2f * h3;
    m0 = fmaxf(m0, h0);
    m1 = fmaxf(m1, h1);
    m2 = fmaxf(m2, h2);
    m3 = fmaxf(m3, h3);
  }
  float4 res = {m0, m1, m2, m3};
  *(float4*)&out[(size_t)ptg * O + oc] = res;
}

// ---------------------------------------------------------------------------
// weight -> bf16 hi/lo split in 16x16x32 B-fragment order (mlp5 only).
// ---------------------------------------------------------------------------
template <int C, int O>
__global__ void k_wprep(const float* __restrict__ w,
                        unsigned short* __restrict__ whi,
                        unsigned short* __restrict__ wlo) {
  int e = blockIdx.x * 256 + threadIdx.x;
  if (e >= C * O) return;
  constexpr int NT = O / 16;
  int j = e & 7;
  int slot = e >> 3;
  int lane = slot & 63;
  int t2 = slot >> 6;
  int nt = t2 % NT, kb = t2 / NT;
  int k = kb * 32 + ((lane >> 4) & 3) * 8 + j;
  int n = nt * 16 + (lane & 15);
  float v = w[(size_t)k * O + n];
  unsigned short h = f2bf(v);
  unsigned short l = f2bf(v - bf2f(h));
  whi[e] = h;
  wlo[e] = l;
}

// ---------------------------------------------------------------------------
// feature matrix -> bf16 hi/lo split in 16x16x32 A-fragment order for mlp5.
// ---------------------------------------------------------------------------
__global__ void k_aprep(const float* __restrict__ x1, const float* __restrict__ x2,
                        const float* __restrict__ x3, const float* __restrict__ x4,
                        unsigned short* __restrict__ ah, unsigned short* __restrict__ al) {
  int e8 = blockIdx.x * 256 + threadIdx.x;
  if (e8 >= 16 * 1024 * 64) return;
  int lane = e8 & 63;
  int mtg = (e8 >> 6) & 1023;
  int kb = e8 >> 16;
  int m = mtg * 16 + (lane & 15);
  int k0 = kb * 32 + ((lane >> 4) & 3) * 8;
  const float* p;
  if (k0 < 64)       p = &x1[(size_t)m * 64 + k0];
  else if (k0 < 128) p = &x2[(size_t)m * 64 + (k0 - 64)];
  else if (k0 < 256) p = &x3[(size_t)m * 128 + (k0 - 128)];
  else               p = &x4[(size_t)m * 256 + (k0 - 256)];
  float4 f0 = *(const float4*)p;
  float4 f1 = *(const float4*)(p + 4);
  float fv[8] = {f0.x, f0.y, f0.z, f0.w, f1.x, f1.y, f1.z, f1.w};
  short8 h8, l8;
#pragma unroll
  for (int j = 0; j < 8; j++) {
    unsigned short h = f2bf(fv[j]);
    unsigned short l = f2bf(fv[j] - bf2f(h));
    h8[j] = (short)h;
    l8[j] = (short)l;
  }
  *(short8*)&ah[(size_t)e8 * 8] = h8;
  *(short8*)&al[(size_t)e8 * 8] = l8;
}

// ---------------------------------------------------------------------------
// point MLP 512->1024 as split-bf16 MFMA GEMM, no LDS, no barriers.
// ---------------------------------------------------------------------------
__global__ __launch_bounds__(256) void k_mlp5(const unsigned short* __restrict__ a5h,
                                              const unsigned short* __restrict__ a5l,
                                              const unsigned short* __restrict__ w5h,
                                              const unsigned short* __restrict__ w5l,
                                              const float* __restrict__ g5,
                                              const float* __restrict__ b5,
                                              float* __restrict__ pmax,
                                              float* __restrict__ psum) {
  const int mtb = blockIdx.x;
  const int ntb = blockIdx.y;
  const int tid = threadIdx.x;
  const int lane = tid & 63;
  const int nsl = tid >> 6;

  f32x4 acc[8][2];
#pragma unroll
  for (int mt = 0; mt < 8; mt++)
#pragma unroll
    for (int t = 0; t < 2; t++) acc[mt][t] = (f32x4){0.f, 0.f, 0.f, 0.f};

  for (int kb = 0; kb < 16; kb++) {
    short8 bh[2], bl[2];
#pragma unroll
    for (int t = 0; t < 2; t++) {
      int ntg = ntb * 8 + nsl * 2 + t;
      size_t widx = ((size_t)(kb * 64 + ntg) * 64 + lane) * 8;
      bh[t] = *(const short8*)&w5h[widx];
      bl[t] = *(const short8*)&w5l[widx];
    }
#pragma unroll
    for (int mt = 0; mt < 8; mt++) {
      size_t aidx = (((size_t)kb * 1024 + mtb * 8 + mt) * 64 + lane) * 8;
      short8 ah = *(const short8*)&a5h[aidx];
      short8 al = *(const short8*)&a5l[aidx];
#pragma unroll
      for (int t = 0; t < 2; t++) {
        acc[mt][t] = __builtin_amdgcn_mfma_f32_16x16x32_bf16(ah, bh[t], acc[mt][t], 0, 0, 0);
        acc[mt][t] = __builtin_amdgcn_mfma_f32_16x16x32_bf16(ah, bl[t], acc[mt][t], 0, 0, 0);
        acc[mt][t] = __builtin_amdgcn_mfma_f32_16x16x32_bf16(al, bh[t], acc[mt][t], 0, 0, 0);
      }
    }
  }

#pragma unroll
  for (int t = 0; t < 2; t++) {
    int o = ntb * 128 + (nsl * 2 + t) * 16 + (lane & 15);
    float gv = g5[o], bv = b5[o];
    float mx = -3.0e38f, sm = 0.f;
#pragma unroll
    for (int mt = 0; mt < 8; mt++)
#pragma unroll
      for (int r = 0; r < 4; r++) {
        float h = acc[mt][t][r] * gv + bv;
        h = (h >= 0.f) ? h : 0.2f * h;
        mx = fmaxf(mx, h);
        sm += h;
      }
    mx = fmaxf(mx, __shfl_xor(mx, 16));
    mx = fmaxf(mx, __shfl_xor(mx, 32));
    sm += __shfl_xor(sm, 16);
    sm += __shfl_xor(sm, 32);
    if (lane < 16) {
      pmax[(size_t)mtb * 1024 + o] = mx;
      psum[(size_t)mtb * 1024 + o] = sm;
    }
  }
}

// ---------------------------------------------------------------------------
// reduce tile partials -> pooled (B, 2048) = [max(1024), mean(1024)]
// ---------------------------------------------------------------------------
__global__ void k_pool(const float* __restrict__ pmax, const float* __restrict__ psum,
                       float* __restrict__ pooled) {
  int i = blockIdx.x * 256 + threadIdx.x;
  if (i >= NBATCH * 1024) return;
  int b = i / 1024, e = i - b * 1024;
  constexpr int NT = NPTS / 128;
  float mx = -3.0e38f, sm = 0.f;
  for (int t = 0; t < NT; t++) {
    mx = fmaxf(mx, pmax[((size_t)b * NT + t) * 1024 + e]);
    sm += psum[((size_t)b * NT + t) * 1024 + e];
  }
  pooled[(size_t)b * 2048 + e] = mx;
  pooled[(size_t)b * 2048 + 1024 + e] = sm * (1.0f / NPTS);
}

// ---------------------------------------------------------------------------
// head layer 1: h1g[b,o] = leaky((pooled[b,:] @ wl1)[o] * g6[o] + b6[o]).
// ---------------------------------------------------------------------------
__global__ __launch_bounds__(256) void k_head1(const float* __restrict__ pooled,
                                               const float* __restrict__ wl1,
                                               const float* __restrict__ g6,
                                               const float* __restrict__ b6,
                                               float* __restrict__ h1g) {
  const int os = blockIdx.x;
  const int b = blockIdx.y;
  const int tid = threadIdx.x;
  const int lane = tid & 63;
  const int ks = tid >> 6;
  const int o = os * 64 + lane;
  __shared__ float pl[2048];
  __shared__ float part[4][64];

  for (int i = tid; i < 2048; i += 256) pl[i] = pooled[(size_t)b * 2048 + i];
  __syncthreads();

  float a = 0.f;
  const int c0 = ks * 512;
  for (int c = 0; c < 512; c++)
    a += pl[c0 + c] * wl1[(size_t)(c0 + c) * 512 + o];
  part[ks][lane] = a;
  __syncthreads();

  if (ks == 0) {
    float s = part[0][lane];
    s += part[1][lane];
    s += part[2][lane];
    s += part[3][lane];
    s = s * g6[o] + b6[o];
    h1g[(size_t)b * 512 + o] = (s >= 0.f) ? s : 0.2f * s;
  }
}

// ---------------------------------------------------------------------------
// head layers 2+3: 512 ->(bias,affine,leaky) 256 -> 40 (+bias).
// ---------------------------------------------------------------------------
__global__ __launch_bounds__(256) void k_head23(const float* __restrict__ h1g,
                                                const float* __restrict__ wl2,
                                                const float* __restrict__ bl2,
                                                const float* __restrict__ g7,
                                                const float* __restrict__ b7,
                                                const float* __restrict__ wl3,
                                                const float* __restrict__ bl3,
                                                float* __restrict__ out) {
  const int b = blockIdx.x;
  const int tid = threadIdx.x;
  __shared__ float h1[512];
  __shared__ float h2[256];

  for (int i = tid; i < 512; i += 256) h1[i] = h1g[(size_t)b * 512 + i];
  __syncthreads();

  {
    float a = 0.f;
    for (int c = 0; c < 512; c++) a += h1[c] * wl2[(size_t)c * 256 + tid];
    a = (a + bl2[tid]) * g7[tid] + b7[tid];
    h2[tid] = (a >= 0.f) ? a : 0.2f * a;
  }
  __syncthreads();

  if (tid < 40) {
    float a = bl3[tid];
    for (int c = 0; c < 256; c++) a += h2[c] * wl3[(size_t)c * 40 + tid];
    out[(size_t)b * 40 + tid] = a;
  }
}

// ---------------------------------------------------------------------------
extern "C" void kernel_launch(void* const* d_in, const int* in_sizes, int n_in,
                              void* d_out, int out_size, void* d_ws, size_t ws_size,
                              hipStream_t stream) {
  (void)in_sizes; (void)n_in; (void)out_size;
  const float* x   = (const float*)d_in[0];
  const float* w1  = (const float*)d_in[1];
  const float* g1  = (const float*)d_in[2];
  const float* b1  = (const float*)d_in[3];
  const float* w2  = (const float*)d_in[4];
  const float* g2  = (const float*)d_in[5];
  const float* b2  = (const float*)d_in[6];
  const float* w3  = (const float*)d_in[7];
  const float* g3  = (const float*)d_in[8];
  const float* b3  = (const float*)d_in[9];
  const float* w4  = (const float*)d_in[10];
  const float* g4  = (const float*)d_in[11];
  const float* b4  = (const float*)d_in[12];
  const float* w5  = (const float*)d_in[13];
  const float* g5  = (const float*)d_in[14];
  const float* b5  = (const float*)d_in[15];
  const float* wl1 = (const float*)d_in[16];
  const float* g6  = (const float*)d_in[17];
  const float* b6  = (const float*)d_in[18];
  const float* wl2 = (const float*)d_in[19];
  const float* bl2 = (const float*)d_in[20];
  const float* g7  = (const float*)d_in[21];
  const float* b7  = (const float*)d_in[22];
  const float* wl3 = (const float*)d_in[23];
  const float* bl3 = (const float*)d_in[24];

  float* ws = (float*)d_ws;
  size_t off = 0;
  float* h0 = ws + off;   off += (size_t)NBATCH * NPTS * 3;
  float* x1 = ws + off;   off += (size_t)NBATCH * NPTS * 64;
  float* x2 = ws + off;   off += (size_t)NBATCH * NPTS * 64;
  float* x3 = ws + off;   off += (size_t)NBATCH * NPTS * 128;
  float* x4 = ws + off;   off += (size_t)NBATCH * NPTS * 256;
  int* knn = (int*)(ws + off); off += (size_t)NBATCH * NPTS * KNN;
  float* pmax = ws + off; off += (size_t)(NPTS / 128) * NBATCH * 1024;
  float* psum = ws + off; off += (size_t)(NPTS / 128) * NBATCH * 1024;
  float* pooled = ws + off; off += (size_t)NBATCH * 2048;
  float* h1g = ws + off;  off += (size_t)NBATCH * 512;
  float* t0buf = ws + off;  off += (size_t)NBATCH * NPTS * 256;  // max O
  unsigned short* w5h = (unsigned short*)(ws + off); off += 512 * 1024 / 2 * 2;
  unsigned short* w5l = w5h + 512 * 1024;
  unsigned short* a5h = (unsigned short*)(ws + off); off += (size_t)16384 * 512 / 2 * 2;
  unsigned short* a5l = a5h + (size_t)16384 * 512;
  float* dist = ws + off;  // adaptive: nb_grp * NPTS * NPTS floats, placed last

  // ybuf (max NBATCH*NPTS*256 floats) aliases the a5h/a5l region: it is dead
  // before k_aprep writes a5h (stream-serial), and the region is 2x larger.
  float* ybuf = (float*)a5h;

  size_t avail = ws_size / 4 - off;
  int nb_grp = 8;
  while (nb_grp > 1 && (size_t)nb_grp * NPTS * NPTS > avail) nb_grp >>= 1;

  constexpr int NTRI = (NPTS / 64) * (NPTS / 64 + 1) / 2;  // 528

  k_transpose<<<(NBATCH * NPTS * 3 + 255) / 256, 256, 0, stream>>>(x, h0);

  // mlp5 weight hi/lo fragment prep (depends only on inputs -- run up front)
  k_wprep<512, 1024><<<(512 * 1024 + 255) / 256, 256, 0, stream>>>(w5, w5h, w5l);

  // ---- edge conv 1 (C=3 -> O=64): fused register kNN + GEMM-gather
  k_knn3<<<dim3(NPTS / 4, NBATCH), 256, 0, stream>>>(h0, knn);
  k_t3<<<(NBATCH * NPTS * 64 + 255) / 256, 256, 0, stream>>>(h0, w1, ybuf, t0buf);
  k_egather<64><<<NBATCH * NPTS / 16, 256, 0, stream>>>(ybuf, t0buf, knn, g1, b1, x1);

  // ---- edge conv 2 (C=64 -> O=64)
  for (int b0 = 0; b0 < NBATCH; b0 += nb_grp) {
    k_dist<64><<<dim3(NTRI, 1, nb_grp), 256, 0, stream>>>(
        x1 + (size_t)b0 * NPTS * 64, dist);
    k_topk<<<dim3(NPTS / 4, nb_grp), 256, 0, stream>>>(dist,
                                                       knn + (size_t)b0 * NPTS * KNN);
  }
  k_t0<64, 64><<<dim3(NBATCH * NPTS / 128, 1, 2), 256, 0, stream>>>(x1, w2, ybuf,
                                                                    t0buf);
  k_egather<64><<<NBATCH * NPTS / 16, 256, 0, stream>>>(ybuf, t0buf, knn, g2, b2, x2);

  // ---- edge conv 3 (C=64 -> O=128)
  for (int b0 = 0; b0 < NBATCH; b0 += nb_grp) {
    k_dist<64><<<dim3(NTRI, 1, nb_grp), 256, 0, stream>>>(
        x2 + (size_t)b0 * NPTS * 64, dist);
    k_topk<<<dim3(NPTS / 4, nb_grp), 256, 0, stream>>>(dist,
                                                       knn + (size_t)b0 * NPTS * KNN);
  }
  k_t0<64, 128><<<dim3(NBATCH * NPTS / 128, 2, 2), 256, 0, stream>>>(x2, w3, ybuf,
                                                                     t0buf);
  k_egather<128><<<NBATCH * NPTS / 8, 256, 0, stream>>>(ybuf, t0buf, knn, g3, b3, x3);

  // ---- edge conv 4 (C=128 -> O=256)
  for (int b0 = 0; b0 < NBATCH; b0 += nb_grp) {
    k_dist128<<<dim3(NTRI, 1, nb_grp), 256, 0, stream>>>(
        x3 + (size_t)b0 * NPTS * 128, dist);
    k_topk<<<dim3(NPTS / 4, nb_grp), 256, 0, stream>>>(dist,
                                                       knn + (size_t)b0 * NPTS * KNN);
  }
  k_t0<128, 256><<<dim3(NBATCH * NPTS / 128, 4, 2), 256, 0, stream>>>(x3, w4, ybuf,
                                                                      t0buf);
  k_egather<256><<<NBATCH * NPTS / 4, 256, 0, stream>>>(ybuf, t0buf, knn, g4, b4, x4);

  // ---- point MLP (split-bf16 MFMA GEMM) + pooling + head
  k_aprep<<<(16 * 1024 * 64 + 255) / 256, 256, 0, stream>>>(x1, x2, x3, x4, a5h, a5l);
  k_mlp5<<<dim3(NBATCH * NPTS / 128, 8), 256, 0, stream>>>(a5h, a5l, w5h, w5l, g5, b5,
                                                           pmax, psum);
  k_pool<<<(NBATCH * 1024 + 255) / 256, 256, 0, stream>>>(pmax, psum, pooled);
  k_head1<<<dim3(8, NBATCH), 256, 0, stream>>>(pooled, wl1, g6, b6, h1g);
  k_head23<<<NBATCH, 256, 0, stream>>>(h1g, wl2, bl2, g7, b7, wl3, bl3,
                                       (float*)d_out);
}

// Round 11
// 646.724 us; speedup vs baseline: 1.0408x; 1.0201x over previous
//
#include <hip/hip_runtime.h>
#include <cstddef>
#include <cstdint>

#define NBATCH 8
#define NPTS   2048
#define KNN    20

typedef __attribute__((ext_vector_type(8))) short short8;
typedef __attribute__((ext_vector_type(4))) float f32x4;

__device__ __forceinline__ unsigned short f2bf(float f) {
  unsigned u = __float_as_uint(f);
  u += 0x7fff + ((u >> 16) & 1);   // round-to-nearest-even
  return (unsigned short)(u >> 16);
}
__device__ __forceinline__ float bf2f(unsigned short h) {
  return __uint_as_float(((unsigned)h) << 16);
}

// monotone float -> orderable uint (ascending uint == ascending float)
__device__ __forceinline__ unsigned f2ord(float f) {
  unsigned u = __float_as_uint(f);
  return (u & 0x80000000u) ? ~u : (u | 0x80000000u);
}

// ---------------------------------------------------------------------------
// 64-lane bitonic sort, ascending across lanes. 21 compare-exchange stages.
// ---------------------------------------------------------------------------
template <typename T>
__device__ __forceinline__ T bitonic_sort_asc(T key, int lane) {
#pragma unroll
  for (int k = 2; k <= 64; k <<= 1) {
#pragma unroll
    for (int j = k >> 1; j > 0; j >>= 1) {
      T other = __shfl_xor(key, j);
      bool takemax = ((lane & k) == 0) != ((lane & j) == 0);
      key = takemax ? (key > other ? key : other)
                    : (key < other ? key : other);
    }
  }
  return key;
}

// ---------------------------------------------------------------------------
// exact serial fallback (ord-space port of the R15 top-2-cache extractor).
// Only taken when >64 values tie above the threshold -- effectively never.
// ---------------------------------------------------------------------------
__device__ void wave_top20_serial(const unsigned (&v)[32], int lane,
                                  int* __restrict__ row_out) {
  unsigned m1 = 0, m2 = 0;
  int i1 = 0, i2 = 0;
#pragma unroll
  for (int i = 0; i < 32; i++) {
    unsigned x = v[i];
    if (x > m1) { m2 = m1; i2 = i1; m1 = x; i1 = i; }
    else if (x > m2) { m2 = x; i2 = i; }
  }

  unsigned dm = 0;
  int cnt = 2;
  int keep = 0;
  for (int k = 0; k < KNN; k++) {
    unsigned rv = m1;
    int ri = i1 * 64 + lane;
#pragma unroll
    for (int off = 32; off > 0; off >>= 1) {
      unsigned ov = __shfl_down(rv, off);
      int oi = __shfl_down(ri, off);
      if (ov > rv || (ov == rv && oi < ri)) { rv = ov; ri = oi; }
    }
    int wi = __shfl(ri, 0);
    if (lane == k) keep = wi;
    if ((wi & 63) == lane) {
      dm |= 1u << (wi >> 6);
      if (cnt == 2) {
        m1 = m2; i1 = i2; cnt = 1;
      } else {
        m1 = 0; i1 = 0; m2 = 0; i2 = 0;
#pragma unroll
        for (int i = 0; i < 32; i++)
          if (!((dm >> i) & 1)) {
            unsigned x = v[i];
            if (x > m1) { m2 = m1; i2 = i1; m1 = x; i1 = i; }
            else if (x > m2) { m2 = x; i2 = i; }
          }
        cnt = 2;
      }
    }
  }
  if (lane < KNN) row_out[lane] = keep;
}

// ---------------------------------------------------------------------------
// wave-level exact top-20 over 2048 candidates (ord space): lane holds 32
// values, global index of v[i] on lane l is i*64 + l. One wave per row.
// R17: threshold (20th-largest lane max) -> ballot-compact candidates into
// LDS -> one 64-lane bitonic sort of packed (value, ~index) keys emits the
// top-20 in order with the lowest-index tie-break.
// ---------------------------------------------------------------------------
__device__ __forceinline__ void wave_top20(const unsigned (&v)[32], int lane,
                                           unsigned long long* cand,
                                           int* __restrict__ row_out) {
  // 1. per-lane max
  unsigned mo = 0;
#pragma unroll
  for (int i = 0; i < 32; i++) mo = (v[i] > mo) ? v[i] : mo;

  // 2. sort the 64 lane maxima; T = 20th largest (ascending lane 44).
  unsigned ms = bitonic_sort_asc(mo, lane);
  unsigned T = __shfl(ms, 64 - KNN);

  // 3. ballot-compact all values >= T into LDS.
  cand[lane] = 0ull;
  int base = 0;
#pragma unroll
  for (int i = 0; i < 32; i++) {
    bool p = v[i] >= T;
    unsigned long long mk = __ballot(p);
    if (p) {
      int pos = base + __popcll(mk & ((1ull << lane) - 1ull));
      if (pos < 64)
        cand[pos] = ((unsigned long long)v[i] << 32) |
                    (unsigned)(~(unsigned)(i * 64 + lane));
    }
    base += (int)__popcll(mk);
  }

  if (base <= 64) {
    // 4. one bitonic sort of packed keys; key = (ord << 32) | ~idx.
    unsigned long long key = cand[lane];
    key = bitonic_sort_asc(key, lane);
    if (lane >= 64 - KNN)
      row_out[63 - lane] = (int)(~(unsigned)key);
  } else {
    wave_top20_serial(v, lane, row_out);
  }
}

// ---------------------------------------------------------------------------
// transpose (B,3,N) -> (B,N,3)
// ---------------------------------------------------------------------------
__global__ void k_transpose(const float* __restrict__ x, float* __restrict__ h0) {
  int i = blockIdx.x * 256 + threadIdx.x;
  if (i >= NBATCH * NPTS * 3) return;
  int c = i % 3;
  int n = (i / 3) % NPTS;
  int b = i / (3 * NPTS);
  h0[i] = x[((size_t)b * 3 + c) * NPTS + n];
}

// ---------------------------------------------------------------------------
// pairwise "distance" pd = 2*dot - sq_n - sq_m. blockIdx.z = batch in group.
// R11-proven 64x64 tile / 4x4 microtile, upper-triangular grid (528 blocks);
// off-diagonal blocks mirror their tile via an LDS bounce (bit-identical).
// NOTE (R12/R13): no 8x8 microtile, no waves/EU pin. R4/R5: NO chunk loops.
// R24/25/26 lesson: scalar NT stores are lane-contiguous -> already
// coalesced; col remaps cost LDS conflicts. TS=67 (odd -> bank spread).
// This is the best-measured configuration (647 us total).
// ---------------------------------------------------------------------------
template <int C>
__global__ __launch_bounds__(256) void k_dist(const float* __restrict__ xg,
                                              float* __restrict__ dist) {
  constexpr int PAD = 4;
  constexpr int S = C + PAD;
  constexpr int TS = 67;
  __shared__ __attribute__((aligned(16))) float rows[64 * S];
  __shared__ __attribute__((aligned(16))) float cols[64 * S];
  __shared__ float sq[128];

  const float* xb = xg + (size_t)blockIdx.z * NPTS * C;
  float* db = dist + (size_t)blockIdx.z * NPTS * NPTS;

  constexpr int T = NPTS / 64;
  int bid = blockIdx.x;
  int rt = 0;
  while (bid >= T - rt) { bid -= T - rt; rt++; }
  const int ct = rt + bid;

  const int tid = threadIdx.x;

  for (int e = tid; e < 64 * C; e += 256) {
    int i = e / C, c = e - i * C;
    rows[i * S + c] = xb[(size_t)(rt * 64 + i) * C + c];
    cols[i * S + c] = xb[(size_t)(ct * 64 + i) * C + c];
  }
  __syncthreads();
  if (tid < 128) {
    const float* p = (tid < 64) ? (rows + tid * S) : (cols + (tid - 64) * S);
    float s = 0.f;
    for (int c = 0; c < C; c++) s += p[c] * p[c];
    sq[tid] = s;
  }
  __syncthreads();

  const int r0 = (tid >> 4) * 4;
  const int c0 = tid & 15;
  float acc[4][4] = {};

  for (int c = 0; c < C; c += 4) {
    float4 ra[4], cb[4];
#pragma unroll
    for (int i = 0; i < 4; i++) ra[i] = *(const float4*)&rows[(r0 + i) * S + c];
#pragma unroll
    for (int j = 0; j < 4; j++) cb[j] = *(const float4*)&cols[(c0 + 16 * j) * S + c];
#pragma unroll
    for (int i = 0; i < 4; i++)
#pragma unroll
      for (int j = 0; j < 4; j++)
        acc[i][j] += ra[i].x * cb[j].x + ra[i].y * cb[j].y +
                     ra[i].z * cb[j].z + ra[i].w * cb[j].w;
  }

  float pd[4][4];
#pragma unroll
  for (int i = 0; i < 4; i++) {
    float sr = sq[r0 + i];
#pragma unroll
    for (int j = 0; j < 4; j++)
      pd[i][j] = 2.f * acc[i][j] - sr - sq[64 + c0 + 16 * j];
  }

#pragma unroll
  for (int i = 0; i < 4; i++)
#pragma unroll
    for (int j = 0; j < 4; j++)
      __builtin_nontemporal_store(
          pd[i][j], &db[(size_t)(rt * 64 + r0 + i) * NPTS + ct * 64 + c0 + 16 * j]);

  if (rt != ct) {
    __syncthreads();
    float* tb = rows;
#pragma unroll
    for (int i = 0; i < 4; i++)
#pragma unroll
      for (int j = 0; j < 4; j++)
        tb[(c0 + 16 * j) * TS + r0 + i] = pd[i][j];
    __syncthreads();
#pragma unroll
    for (int i = 0; i < 4; i++)
#pragma unroll
      for (int j = 0; j < 4; j++)
        __builtin_nontemporal_store(
            tb[(r0 + i) * TS + c0 + 16 * j],
            &db[(size_t)(ct * 64 + r0 + i) * NPTS + rt * 64 + c0 + 16 * j]);
  }
}

// ---------------------------------------------------------------------------
// C=128 dist, single-pass, rows direct from global (R22: 16-lane broadcast,
// L1-resident; bit-identical pd). NT scalar stores (R23).
// ---------------------------------------------------------------------------
__global__ __launch_bounds__(256) void k_dist128(const float* __restrict__ xg,
                                                 float* __restrict__ dist) {
  constexpr int C = 128;
  constexpr int S = C + 4;    // 132
  constexpr int TS = 67;
  __shared__ __attribute__((aligned(16))) float cols[64 * S];
  __shared__ float sq[128];

  const float* xb = xg + (size_t)blockIdx.z * NPTS * C;
  float* db = dist + (size_t)blockIdx.z * NPTS * NPTS;

  constexpr int T = NPTS / 64;
  int bid = blockIdx.x;
  int rt = 0;
  while (bid >= T - rt) { bid -= T - rt; rt++; }
  const int ct = rt + bid;

  const int tid = threadIdx.x;

  for (int e = tid; e < 64 * C; e += 256) {
    int i = e / C, c = e - i * C;
    cols[i * S + c] = xb[(size_t)(ct * 64 + i) * C + c];
  }
  // rows sq straight from global (same scalar ascending order as R11)
  float sr_own = 0.f;
  if (tid < 64) {
    const float* p = xb + (size_t)(rt * 64 + tid) * C;
    for (int c = 0; c < C; c++) sr_own += p[c] * p[c];
  }
  __syncthreads();
  if (tid < 128) {
    if (tid < 64) {
      sq[tid] = sr_own;
    } else {
      const float* p = cols + (tid - 64) * S;
      float s = 0.f;
      for (int c = 0; c < C; c++) s += p[c] * p[c];
      sq[tid] = s;
    }
  }
  __syncthreads();

  const int r0 = (tid >> 4) * 4;
  const int c0 = tid & 15;
  const float* xr0 = xb + (size_t)(rt * 64 + r0) * C;
  const float* xr1 = xr0 + C;
  const float* xr2 = xr1 + C;
  const float* xr3 = xr2 + C;
  float acc[4][4] = {};

  for (int c = 0; c < C; c += 4) {
    float4 ra[4], cb[4];
    ra[0] = *(const float4*)&xr0[c];
    ra[1] = *(const float4*)&xr1[c];
    ra[2] = *(const float4*)&xr2[c];
    ra[3] = *(const float4*)&xr3[c];
#pragma unroll
    for (int j = 0; j < 4; j++) cb[j] = *(const float4*)&cols[(c0 + 16 * j) * S + c];
#pragma unroll
    for (int i = 0; i < 4; i++)
#pragma unroll
      for (int j = 0; j < 4; j++)
        acc[i][j] += ra[i].x * cb[j].x + ra[i].y * cb[j].y +
                     ra[i].z * cb[j].z + ra[i].w * cb[j].w;
  }

  float pd[4][4];
#pragma unroll
  for (int i = 0; i < 4; i++) {
    float sr = sq[r0 + i];
#pragma unroll
    for (int j = 0; j < 4; j++)
      pd[i][j] = 2.f * acc[i][j] - sr - sq[64 + c0 + 16 * j];
  }

#pragma unroll
  for (int i = 0; i < 4; i++)
#pragma unroll
    for (int j = 0; j < 4; j++)
      __builtin_nontemporal_store(
          pd[i][j], &db[(size_t)(rt * 64 + r0 + i) * NPTS + ct * 64 + c0 + 16 * j]);

  if (rt != ct) {
    __syncthreads();   // all cols reads done before reuse as bounce buffer
    float* tb = cols;  // 64*TS = 4288 <= 64*S = 8448 floats
#pragma unroll
    for (int i = 0; i < 4; i++)
#pragma unroll
      for (int j = 0; j < 4; j++)
        tb[(c0 + 16 * j) * TS + r0 + i] = pd[i][j];
    __syncthreads();
#pragma unroll
    for (int i = 0; i < 4; i++)
#pragma unroll
      for (int j = 0; j < 4; j++)
        __builtin_nontemporal_store(
            tb[(r0 + i) * TS + c0 + 16 * j],
            &db[(size_t)(ct * 64 + r0 + i) * NPTS + rt * 64 + c0 + 16 * j]);
  }
}

// ---------------------------------------------------------------------------
// top-20 per row from materialized dist. One wave per row, 4 rows per block.
// Scalar NT reads (R26 lesson: lane-contiguous scalar loads are already
// coalesced; MODE-1 vectorization measured neutral-to-negative).
// ---------------------------------------------------------------------------
__global__ __launch_bounds__(256) void k_topk(const float* __restrict__ dist,
                                              int* __restrict__ idx_out) {
  __shared__ unsigned long long cand[4][64];
  const int wid = threadIdx.x >> 6;
  const int lane = threadIdx.x & 63;
  const int n = blockIdx.x * 4 + wid;
  const int z = blockIdx.y;
  const float* drow = dist + ((size_t)z * NPTS + n) * NPTS;
  int* row_out = idx_out + ((size_t)z * NPTS + n) * KNN;

  unsigned v[32];
#pragma unroll
  for (int i = 0; i < 32; i++)
    v[i] = f2ord(__builtin_nontemporal_load(&drow[i * 64 + lane]));

  wave_top20(v, lane, cand[wid], row_out);
}

// ---------------------------------------------------------------------------
// conv1 fused kNN (C=3): one wave per row, register recompute + wave_top20.
// ---------------------------------------------------------------------------
__global__ __launch_bounds__(256) void k_knn3(const float* __restrict__ x,
                                              int* __restrict__ idx_out) {
  __shared__ unsigned long long cand[4][64];
  const int wid = threadIdx.x >> 6;
  const int lane = threadIdx.x & 63;
  const int n = blockIdx.x * 4 + wid;
  const int b = blockIdx.y;
  const float* xb = x + (size_t)b * NPTS * 3;
  int* row_out = idx_out + ((size_t)b * NPTS + n) * KNN;

  const float qx = xb[n * 3 + 0], qy = xb[n * 3 + 1], qz = xb[n * 3 + 2];
  float qsq = 0.f;
  qsq += qx * qx; qsq += qy * qy; qsq += qz * qz;

  unsigned v[32];
#pragma unroll
  for (int i = 0; i < 32; i++) {
    int m = i * 64 + lane;
    float cx = xb[m * 3 + 0], cy = xb[m * 3 + 1], cz = xb[m * 3 + 2];
    float csq = 0.f;
    csq += cx * cx; csq += cy * cy; csq += cz * cz;
    float acc = 0.f;
    acc += qx * cx; acc += qy * cy; acc += qz * cz;
    v[i] = f2ord(2.f * acc - qsq - csq);
  }

  wave_top20(v, lane, cand[wid], row_out);
}

// ---------------------------------------------------------------------------
// dual dense GEMM: blockIdx.z selects the w row-slice and output buffer.
//   z=0: out = ybuf,  wpart = w          (nb-ctr part)
//   z=1: out = t0buf, wpart = w + C*O    (ctr part)
// R18: gather commutes with the GEMM.
// ---------------------------------------------------------------------------
template <int C, int O>
__global__ __launch_bounds__(256) void k_t0(const float* __restrict__ x,
                                            const float* __restrict__ w,
                                            float* __restrict__ yb,
                                            float* __restrict__ t0b) {
  constexpr int TM = 128, TN = 64, TK = 16;
  __shared__ __attribute__((aligned(16))) float As[TK][TM + 4];
  __shared__ __attribute__((aligned(16))) float Bs[TK][TN + 4];
  const float* wpart = w + (size_t)blockIdx.z * C * O;
  float* outb = blockIdx.z ? t0b : yb;
  const int mt = blockIdx.x, nt = blockIdx.y;
  const int tid = threadIdx.x;
  const int tx = tid & 15, ty = tid >> 4;
  const size_t m0 = (size_t)mt * TM;
  const int n0 = nt * TN;
  float acc[8][4] = {};

  for (int kt = 0; kt < C; kt += TK) {
#pragma unroll
    for (int e = 0; e < 8; e++) {
      int idx = tid + e * 256;
      int m = idx >> 4, k = idx & 15;
      As[k][m] = x[(m0 + m) * C + kt + k];
    }
#pragma unroll
    for (int e = 0; e < 4; e++) {
      int idx = tid + e * 256;
      int k = idx >> 6, nn = idx & 63;
      Bs[k][nn] = wpart[(size_t)(kt + k) * O + n0 + nn];
    }
    __syncthreads();
#pragma unroll
    for (int kk = 0; kk < TK; kk++) {
      float4 a0 = *(const float4*)&As[kk][ty * 8];
      float4 a1 = *(const float4*)&As[kk][ty * 8 + 4];
      float4 b0 = *(const float4*)&Bs[kk][tx * 4];
      float av[8] = {a0.x, a0.y, a0.z, a0.w, a1.x, a1.y, a1.z, a1.w};
      float bb[4] = {b0.x, b0.y, b0.z, b0.w};
#pragma unroll
      for (int i = 0; i < 8; i++)
#pragma unroll
        for (int j = 0; j < 4; j++) acc[i][j] += av[i] * bb[j];
    }
    __syncthreads();
  }
#pragma unroll
  for (int i = 0; i < 8; i++)
#pragma unroll
    for (int j = 0; j < 4; j++)
      outb[(m0 + ty * 8 + i) * O + n0 + tx * 4 + j] = acc[i][j];
}

// ---------------------------------------------------------------------------
// conv1 tiny GEMM (C=3, O=64): one thread per (n,o), computes both the
// (nb-ctr) part y and the ctr part t0 in one pass.
// ---------------------------------------------------------------------------
__global__ void k_t3(const float* __restrict__ x, const float* __restrict__ w,
                     float* __restrict__ y, float* __restrict__ t0) {
  int i = blockIdx.x * 256 + threadIdx.x;
  if (i >= NBATCH * NPTS * 64) return;
  int o = i & 63;
  int n = i >> 6;
  float x0 = x[n * 3 + 0], x1v = x[n * 3 + 1], x2v = x[n * 3 + 2];
  y[i]  = x0 * w[0 * 64 + o] + x1v * w[1 * 64 + o] + x2v * w[2 * 64 + o];
  t0[i] = x0 * w[3 * 64 + o] + x1v * w[4 * 64 + o] + x2v * w[5 * 64 + o];
}

// ---------------------------------------------------------------------------
// edge conv epilogue: out[n,o] = max_k leaky((y[m_k,o] - y[n,o] + t0[n,o])
//                                            * g[o] + b[o]).
// Pure gather-max. grid MUST be NBATCH*NPTS/PPB (R19).
// ---------------------------------------------------------------------------
template <int O>
__global__ __launch_bounds__(256) void k_egather(
    const float* __restrict__ y, const float* __restrict__ t0,
    const int* __restrict__ knn, const float* __restrict__ g,
    const float* __restrict__ bta, float* __restrict__ out) {
  constexpr int TPP = O / 4;              // threads per point
  constexpr int PPB = 256 / TPP;          // points per block
  const int tid = threadIdx.x;
  const int pl = tid / TPP;
  const int oc = (tid % TPP) * 4;
  const int ptg = blockIdx.x * PPB + pl;  // global point index (b*NPTS+n)
  if (ptg >= NBATCH * NPTS) return;
  const int bb = ptg >> 11;               // NPTS = 2048
  const int* kp = knn + (size_t)ptg * KNN;
  const float* yb = y + (size_t)bb * NPTS * O;

  const float4 yc = *(const float4*)&y[(size_t)ptg * O + oc];
  const float4 tc = *(const float4*)&t0[(size_t)ptg * O + oc];
  const float4 gv = *(const float4*)&g[oc];
  const float4 bv = *(const float4*)&bta[oc];
  const float cx = tc.x - yc.x, cy = tc.y - yc.y;
  const float cz = tc.z - yc.z, cw = tc.w - yc.w;

  int midx[KNN];
#pragma unroll
  for (int k = 0; k < KNN; k++) midx[k] = kp[k];

  float4 vv[KNN];
#pragma unroll
  for (int k = 0; k < KNN; k++)
    vv[k] = *(const float4*)&yb[(size_t)midx[k] * O + oc];

  float m0 = -3.0e38f, m1 = -3.0e38f, m2 = -3.0e38f, m3 = -3.0e38f;
#pragma unroll
  for (int k = 0; k < KNN; k++) {
    float h0 = (vv[k].x + cx) * gv.x + bv.x;
    float h1 = (vv[k].y + cy) * gv.y + bv.y;
    float h2 = (vv[k].z + cz) * gv.z + bv.z;
    float h3 = (vv[k].w + cw) * gv.w + bv.w;
    h0 = (h0 >= 0.f) ? h0 : 0.2f * h0;
    h1 = (h1 >= 0.f) ? h1 : 0.2f * h1;
    h2 = (h2 >= 0.f) ? h2 : 0.2f * h2;
    h3 = (h3 >= 0.f) ? h3 : 0.2f * h3;
    m0 = fmaxf(m0, h0);
    m1 = fmaxf(m1, h1);
    m2 = fmaxf(m2, h2);
    m3 = fmaxf(m3, h3);
  }
  float4 res = {m0, m1, m2, m3};
  *(float4*)&out[(size_t)ptg * O + oc] = res;
}

// ---------------------------------------------------------------------------
// weight -> bf16 hi/lo split in 16x16x32 B-fragment order (mlp5 only).
// ---------------------------------------------------------------------------
template <int C, int O>
__global__ void k_wprep(const float* __restrict__ w,
                        unsigned short* __restrict__ whi,
                        unsigned short* __restrict__ wlo) {
  int e = blockIdx.x * 256 + threadIdx.x;
  if (e >= C * O) return;
  constexpr int NT = O / 16;
  int j = e & 7;
  int slot = e >> 3;
  int lane = slot & 63;
  int t2 = slot >> 6;
  int nt = t2 % NT, kb = t2 / NT;
  int k = kb * 32 + ((lane >> 4) & 3) * 8 + j;
  int n = nt * 16 + (lane & 15);
  float v = w[(size_t)k * O + n];
  unsigned short h = f2bf(v);
  unsigned short l = f2bf(v - bf2f(h));
  whi[e] = h;
  wlo[e] = l;
}

// ---------------------------------------------------------------------------
// feature matrix -> bf16 hi/lo split in 16x16x32 A-fragment order for mlp5.
// ---------------------------------------------------------------------------
__global__ void k_aprep(const float* __restrict__ x1, const float* __restrict__ x2,
                        const float* __restrict__ x3, const float* __restrict__ x4,
                        unsigned short* __restrict__ ah, unsigned short* __restrict__ al) {
  int e8 = blockIdx.x * 256 + threadIdx.x;
  if (e8 >= 16 * 1024 * 64) return;
  int lane = e8 & 63;
  int mtg = (e8 >> 6) & 1023;
  int kb = e8 >> 16;
  int m = mtg * 16 + (lane & 15);
  int k0 = kb * 32 + ((lane >> 4) & 3) * 8;
  const float* p;
  if (k0 < 64)       p = &x1[(size_t)m * 64 + k0];
  else if (k0 < 128) p = &x2[(size_t)m * 64 + (k0 - 64)];
  else if (k0 < 256) p = &x3[(size_t)m * 128 + (k0 - 128)];
  else               p = &x4[(size_t)m * 256 + (k0 - 256)];
  float4 f0 = *(const float4*)p;
  float4 f1 = *(const float4*)(p + 4);
  float fv[8] = {f0.x, f0.y, f0.z, f0.w, f1.x, f1.y, f1.z, f1.w};
  short8 h8, l8;
#pragma unroll
  for (int j = 0; j < 8; j++) {
    unsigned short h = f2bf(fv[j]);
    unsigned short l = f2bf(fv[j] - bf2f(h));
    h8[j] = (short)h;
    l8[j] = (short)l;
  }
  *(short8*)&ah[(size_t)e8 * 8] = h8;
  *(short8*)&al[(size_t)e8 * 8] = l8;
}

// ---------------------------------------------------------------------------
// point MLP 512->1024 as split-bf16 MFMA GEMM, no LDS, no barriers.
// ---------------------------------------------------------------------------
__global__ __launch_bounds__(256) void k_mlp5(const unsigned short* __restrict__ a5h,
                                              const unsigned short* __restrict__ a5l,
                                              const unsigned short* __restrict__ w5h,
                                              const unsigned short* __restrict__ w5l,
                                              const float* __restrict__ g5,
                                              const float* __restrict__ b5,
                                              float* __restrict__ pmax,
                                              float* __restrict__ psum) {
  const int mtb = blockIdx.x;
  const int ntb = blockIdx.y;
  const int tid = threadIdx.x;
  const int lane = tid & 63;
  const int nsl = tid >> 6;

  f32x4 acc[8][2];
#pragma unroll
  for (int mt = 0; mt < 8; mt++)
#pragma unroll
    for (int t = 0; t < 2; t++) acc[mt][t] = (f32x4){0.f, 0.f, 0.f, 0.f};

  for (int kb = 0; kb < 16; kb++) {
    short8 bh[2], bl[2];
#pragma unroll
    for (int t = 0; t < 2; t++) {
      int ntg = ntb * 8 + nsl * 2 + t;
      size_t widx = ((size_t)(kb * 64 + ntg) * 64 + lane) * 8;
      bh[t] = *(const short8*)&w5h[widx];
      bl[t] = *(const short8*)&w5l[widx];
    }
#pragma unroll
    for (int mt = 0; mt < 8; mt++) {
      size_t aidx = (((size_t)kb * 1024 + mtb * 8 + mt) * 64 + lane) * 8;
      short8 ah = *(const short8*)&a5h[aidx];
      short8 al = *(const short8*)&a5l[aidx];
#pragma unroll
      for (int t = 0; t < 2; t++) {
        acc[mt][t] = __builtin_amdgcn_mfma_f32_16x16x32_bf16(ah, bh[t], acc[mt][t], 0, 0, 0);
        acc[mt][t] = __builtin_amdgcn_mfma_f32_16x16x32_bf16(ah, bl[t], acc[mt][t], 0, 0, 0);
        acc[mt][t] = __builtin_amdgcn_mfma_f32_16x16x32_bf16(al, bh[t], acc[mt][t], 0, 0, 0);
      }
    }
  }

#pragma unroll
  for (int t = 0; t < 2; t++) {
    int o = ntb * 128 + (nsl * 2 + t) * 16 + (lane & 15);
    float gv = g5[o], bv = b5[o];
    float mx = -3.0e38f, sm = 0.f;
#pragma unroll
    for (int mt = 0; mt < 8; mt++)
#pragma unroll
      for (int r = 0; r < 4; r++) {
        float h = acc[mt][t][r] * gv + bv;
        h = (h >= 0.f) ? h : 0.2f * h;
        mx = fmaxf(mx, h);
        sm += h;
      }
    mx = fmaxf(mx, __shfl_xor(mx, 16));
    mx = fmaxf(mx, __shfl_xor(mx, 32));
    sm += __shfl_xor(sm, 16);
    sm += __shfl_xor(sm, 32);
    if (lane < 16) {
      pmax[(size_t)mtb * 1024 + o] = mx;
      psum[(size_t)mtb * 1024 + o] = sm;
    }
  }
}

// ---------------------------------------------------------------------------
// reduce tile partials -> pooled (B, 2048) = [max(1024), mean(1024)]
// ---------------------------------------------------------------------------
__global__ void k_pool(const float* __restrict__ pmax, const float* __restrict__ psum,
                       float* __restrict__ pooled) {
  int i = blockIdx.x * 256 + threadIdx.x;
  if (i >= NBATCH * 1024) return;
  int b = i / 1024, e = i - b * 1024;
  constexpr int NT = NPTS / 128;
  float mx = -3.0e38f, sm = 0.f;
  for (int t = 0; t < NT; t++) {
    mx = fmaxf(mx, pmax[((size_t)b * NT + t) * 1024 + e]);
    sm += psum[((size_t)b * NT + t) * 1024 + e];
  }
  pooled[(size_t)b * 2048 + e] = mx;
  pooled[(size_t)b * 2048 + 1024 + e] = sm * (1.0f / NPTS);
}

// ---------------------------------------------------------------------------
// head layer 1: h1g[b,o] = leaky((pooled[b,:] @ wl1)[o] * g6[o] + b6[o]).
// ---------------------------------------------------------------------------
__global__ __launch_bounds__(256) void k_head1(const float* __restrict__ pooled,
                                               const float* __restrict__ wl1,
                                               const float* __restrict__ g6,
                                               const float* __restrict__ b6,
                                               float* __restrict__ h1g) {
  const int os = blockIdx.x;
  const int b = blockIdx.y;
  const int tid = threadIdx.x;
  const int lane = tid & 63;
  const int ks = tid >> 6;
  const int o = os * 64 + lane;
  __shared__ float pl[2048];
  __shared__ float part[4][64];

  for (int i = tid; i < 2048; i += 256) pl[i] = pooled[(size_t)b * 2048 + i];
  __syncthreads();

  float a = 0.f;
  const int c0 = ks * 512;
  for (int c = 0; c < 512; c++)
    a += pl[c0 + c] * wl1[(size_t)(c0 + c) * 512 + o];
  part[ks][lane] = a;
  __syncthreads();

  if (ks == 0) {
    float s = part[0][lane];
    s += part[1][lane];
    s += part[2][lane];
    s += part[3][lane];
    s = s * g6[o] + b6[o];
    h1g[(size_t)b * 512 + o] = (s >= 0.f) ? s : 0.2f * s;
  }
}

// ---------------------------------------------------------------------------
// head layers 2+3: 512 ->(bias,affine,leaky) 256 -> 40 (+bias).
// ---------------------------------------------------------------------------
__global__ __launch_bounds__(256) void k_head23(const float* __restrict__ h1g,
                                                const float* __restrict__ wl2,
                                                const float* __restrict__ bl2,
                                                const float* __restrict__ g7,
                                                const float* __restrict__ b7,
                                                const float* __restrict__ wl3,
                                                const float* __restrict__ bl3,
                                                float* __restrict__ out) {
  const int b = blockIdx.x;
  const int tid = threadIdx.x;
  __shared__ float h1[512];
  __shared__ float h2[256];

  for (int i = tid; i < 512; i += 256) h1[i] = h1g[(size_t)b * 512 + i];
  __syncthreads();

  {
    float a = 0.f;
    for (int c = 0; c < 512; c++) a += h1[c] * wl2[(size_t)c * 256 + tid];
    a = (a + bl2[tid]) * g7[tid] + b7[tid];
    h2[tid] = (a >= 0.f) ? a : 0.2f * a;
  }
  __syncthreads();

  if (tid < 40) {
    float a = bl3[tid];
    for (int c = 0; c < 256; c++) a += h2[c] * wl3[(size_t)c * 40 + tid];
    out[(size_t)b * 40 + tid] = a;
  }
}

// ---------------------------------------------------------------------------
extern "C" void kernel_launch(void* const* d_in, const int* in_sizes, int n_in,
                              void* d_out, int out_size, void* d_ws, size_t ws_size,
                              hipStream_t stream) {
  (void)in_sizes; (void)n_in; (void)out_size;
  const float* x   = (const float*)d_in[0];
  const float* w1  = (const float*)d_in[1];
  const float* g1  = (const float*)d_in[2];
  const float* b1  = (const float*)d_in[3];
  const float* w2  = (const float*)d_in[4];
  const float* g2  = (const float*)d_in[5];
  const float* b2  = (const float*)d_in[6];
  const float* w3  = (const float*)d_in[7];
  const float* g3  = (const float*)d_in[8];
  const float* b3  = (const float*)d_in[9];
  const float* w4  = (const float*)d_in[10];
  const float* g4  = (const float*)d_in[11];
  const float* b4  = (const float*)d_in[12];
  const float* w5  = (const float*)d_in[13];
  const float* g5  = (const float*)d_in[14];
  const float* b5  = (const float*)d_in[15];
  const float* wl1 = (const float*)d_in[16];
  const float* g6  = (const float*)d_in[17];
  const float* b6  = (const float*)d_in[18];
  const float* wl2 = (const float*)d_in[19];
  const float* bl2 = (const float*)d_in[20];
  const float* g7  = (const float*)d_in[21];
  const float* b7  = (const float*)d_in[22];
  const float* wl3 = (const float*)d_in[23];
  const float* bl3 = (const float*)d_in[24];

  float* ws = (float*)d_ws;
  size_t off = 0;
  float* h0 = ws + off;   off += (size_t)NBATCH * NPTS * 3;
  float* x1 = ws + off;   off += (size_t)NBATCH * NPTS * 64;
  float* x2 = ws + off;   off += (size_t)NBATCH * NPTS * 64;
  float* x3 = ws + off;   off += (size_t)NBATCH * NPTS * 128;
  float* x4 = ws + off;   off += (size_t)NBATCH * NPTS * 256;
  int* knn = (int*)(ws + off); off += (size_t)NBATCH * NPTS * KNN;
  float* pmax = ws + off; off += (size_t)(NPTS / 128) * NBATCH * 1024;
  float* psum = ws + off; off += (size_t)(NPTS / 128) * NBATCH * 1024;
  float* pooled = ws + off; off += (size_t)NBATCH * 2048;
  float* h1g = ws + off;  off += (size_t)NBATCH * 512;
  float* t0buf = ws + off;  off += (size_t)NBATCH * NPTS * 256;  // max O
  unsigned short* w5h = (unsigned short*)(ws + off); off += 512 * 1024 / 2 * 2;
  unsigned short* w5l = w5h + 512 * 1024;
  unsigned short* a5h = (unsigned short*)(ws + off); off += (size_t)16384 * 512 / 2 * 2;
  unsigned short* a5l = a5h + (size_t)16384 * 512;
  float* dist = ws + off;  // adaptive: nb_grp * NPTS * NPTS floats, placed last

  // ybuf (max NBATCH*NPTS*256 floats) aliases the a5h/a5l region: it is dead
  // before k_aprep writes a5h (stream-serial), and the region is 2x larger.
  float* ybuf = (float*)a5h;

  size_t avail = ws_size / 4 - off;
  int nb_grp = 8;
  while (nb_grp > 1 && (size_t)nb_grp * NPTS * NPTS > avail) nb_grp >>= 1;

  constexpr int NTRI = (NPTS / 64) * (NPTS / 64 + 1) / 2;  // 528

  k_transpose<<<(NBATCH * NPTS * 3 + 255) / 256, 256, 0, stream>>>(x, h0);

  // mlp5 weight hi/lo fragment prep (depends only on inputs -- run up front)
  k_wprep<512, 1024><<<(512 * 1024 + 255) / 256, 256, 0, stream>>>(w5, w5h, w5l);

  // ---- edge conv 1 (C=3 -> O=64): fused register kNN + GEMM-gather
  k_knn3<<<dim3(NPTS / 4, NBATCH), 256, 0, stream>>>(h0, knn);
  k_t3<<<(NBATCH * NPTS * 64 + 255) / 256, 256, 0, stream>>>(h0, w1, ybuf, t0buf);
  k_egather<64><<<NBATCH * NPTS / 16, 256, 0, stream>>>(ybuf, t0buf, knn, g1, b1, x1);

  // ---- edge conv 2 (C=64 -> O=64)
  for (int b0 = 0; b0 < NBATCH; b0 += nb_grp) {
    k_dist<64><<<dim3(NTRI, 1, nb_grp), 256, 0, stream>>>(
        x1 + (size_t)b0 * NPTS * 64, dist);
    k_topk<<<dim3(NPTS / 4, nb_grp), 256, 0, stream>>>(dist,
                                                       knn + (size_t)b0 * NPTS * KNN);
  }
  k_t0<64, 64><<<dim3(NBATCH * NPTS / 128, 1, 2), 256, 0, stream>>>(x1, w2, ybuf,
                                                                    t0buf);
  k_egather<64><<<NBATCH * NPTS / 16, 256, 0, stream>>>(ybuf, t0buf, knn, g2, b2, x2);

  // ---- edge conv 3 (C=64 -> O=128)
  for (int b0 = 0; b0 < NBATCH; b0 += nb_grp) {
    k_dist<64><<<dim3(NTRI, 1, nb_grp), 256, 0, stream>>>(
        x2 + (size_t)b0 * NPTS * 64, dist);
    k_topk<<<dim3(NPTS / 4, nb_grp), 256, 0, stream>>>(dist,
                                                       knn + (size_t)b0 * NPTS * KNN);
  }
  k_t0<64, 128><<<dim3(NBATCH * NPTS / 128, 2, 2), 256, 0, stream>>>(x2, w3, ybuf,
                                                                     t0buf);
  k_egather<128><<<NBATCH * NPTS / 8, 256, 0, stream>>>(ybuf, t0buf, knn, g3, b3, x3);

  // ---- edge conv 4 (C=128 -> O=256)
  for (int b0 = 0; b0 < NBATCH; b0 += nb_grp) {
    k_dist128<<<dim3(NTRI, 1, nb_grp), 256, 0, stream>>>(
        x3 + (size_t)b0 * NPTS * 128, dist);
    k_topk<<<dim3(NPTS / 4, nb_grp), 256, 0, stream>>>(dist,
                                                       knn + (size_t)b0 * NPTS * KNN);
  }
  k_t0<128, 256><<<dim3(NBATCH * NPTS / 128, 4, 2), 256, 0, stream>>>(x3, w4, ybuf,
                                                                      t0buf);
  k_egather<256><<<NBATCH * NPTS / 4, 256, 0, stream>>>(ybuf, t0buf, knn, g4, b4, x4);

  // ---- point MLP (split-bf16 MFMA GEMM) + pooling + head
  k_aprep<<<(16 * 1024 * 64 + 255) / 256, 256, 0, stream>>>(x1, x2, x3, x4, a5h, a5l);
  k_mlp5<<<dim3(NBATCH * NPTS / 128, 8), 256, 0, stream>>>(a5h, a5l, w5h, w5l, g5, b5,
                                                           pmax, psum);
  k_pool<<<(NBATCH * 1024 + 255) / 256, 256, 0, stream>>>(pmax, psum, pooled);
  k_head1<<<dim3(8, NBATCH), 256, 0, stream>>>(pooled, wl1, g6, b6, h1g);
  k_head23<<<NBATCH, 256, 0, stream>>>(h1g, wl2, bl2, g7, b7, wl3, bl3,
                                       (float*)d_out);
}